// Round 17
// baseline (295.271 us; speedup 1.0000x reference)
//
#include <hip/hip_runtime.h>

#define N_NODES_C 100000
#define N_EDGES_C 800000
#define FEATS 100
#define NCLS 50
#define GENE 20000
#define SCAN_BLK 1024
#define SCAN_NBLK ((N_NODES_C + SCAN_BLK - 1) / SCAN_BLK)   // 98
#define KPAD 128                                             // padded K (4 x 32)
#define EDGES_PER_BLK 2048
#define GRP_BLKS ((N_EDGES_C + EDGES_PER_BLK - 1) / EDGES_PER_BLK)  // 391 per group
#define NGRP 4
#define GRP_NODES (N_NODES_C / NGRP)                         // 25000
// mega_prep block ranges
#define CONV_BLKS 12500                                      // N*32/256
#define DEG_BLKS (NGRP * GRP_BLKS)                           // 1564
#define WPREP_BLKS 8
#define MEGA_BLKS (CONV_BLKS + DEG_BLKS + WPREP_BLKS)        // 14072

typedef short bf16x8 __attribute__((ext_vector_type(8)));
typedef float f32x4  __attribute__((ext_vector_type(4)));

// bf16 helpers (RNE pack, shift-unpack)
__device__ __forceinline__ unsigned short f2bf(float f) {
    unsigned int x = __float_as_uint(f);
    return (unsigned short)((x + 0x7FFFu + ((x >> 16) & 1u)) >> 16);
}
__device__ __forceinline__ unsigned int pack2(float lo, float hi) {
    return (unsigned int)f2bf(lo) | ((unsigned int)f2bf(hi) << 16);
}
__device__ __forceinline__ float bflo(unsigned int u) { return __uint_as_float(u << 16); }
__device__ __forceinline__ float bfhi(unsigned int u) { return __uint_as_float(u & 0xFFFF0000u); }

// ---------------------------------------------------------------------------
// mega_prep: three independent prep jobs, block-range dispatched.
//   [0, 12500)        : features f32 [N][100] -> bf16 [N][KPAD] (zero-pad)
//   [12500, 14064)    : degree count, 4-group dst-partitioned
//   [14064, 14072)    : pad W1/W2 -> [112][KPAD], lin_w -> [64][KPAD] bf16
// deg is memset to 0 by the preceding stream op.
// ---------------------------------------------------------------------------
__global__ __launch_bounds__(256) void mega_prep_kernel(
        const float* __restrict__ features,
        const int* __restrict__ dst,
        const float* __restrict__ W1,
        const float* __restrict__ W2,
        const float* __restrict__ LW,
        unsigned short* __restrict__ fbf,
        int* __restrict__ deg,
        unsigned short* __restrict__ Wp1,
        unsigned short* __restrict__ Wp2,
        unsigned short* __restrict__ LWp) {
    const int bid = blockIdx.x;
    const int tid = threadIdx.x;

    if (bid < CONV_BLKS) {
        // ---- feature conversion ----
        int i = bid * 256 + tid;                 // < 3.2M exactly
        int node = i >> 5;
        int sl = i & 31;
        uint2 o = make_uint2(0u, 0u);
        if (sl < 25) {
            float4 v = reinterpret_cast<const float4*>(features + (size_t)node * FEATS)[sl];
            o.x = pack2(v.x, v.y);
            o.y = pack2(v.z, v.w);
        }
        reinterpret_cast<uint2*>(fbf + (size_t)node * KPAD)[sl] = o;
    } else if (bid < CONV_BLKS + DEG_BLKS) {
        // ---- degree count, 4-group partitioned ----
        const int b2 = bid - CONV_BLKS;
        const int g   = b2 & (NGRP - 1);
        const int blk = b2 >> 2;
        const int lo  = g * GRP_NODES;
        const int hi  = lo + GRP_NODES;
        const int base = blk * EDGES_PER_BLK + tid * 8;
        #pragma unroll
        for (int half = 0; half < 2; ++half) {
            const int e = base + half * 4;
            if (e >= N_EDGES_C) break;
            int4 d4 = *reinterpret_cast<const int4*>(dst + e);
            const int ds[4] = {d4.x, d4.y, d4.z, d4.w};
            #pragma unroll
            for (int i = 0; i < 4; ++i) {
                if (ds[i] >= lo && ds[i] < hi) atomicAdd(&deg[ds[i]], 1);
            }
        }
    } else {
        // ---- weight pad/convert ----
        const int wb = bid - (CONV_BLKS + DEG_BLKS);
        for (int i = wb * 256 + tid; i < 112 * KPAD; i += WPREP_BLKS * 256) {
            int r = i >> 7;
            int c = i & 127;
            bool in100 = (r < 100) && (c < 100);
            Wp1[i] = in100 ? f2bf(W1[r * 100 + c]) : (unsigned short)0;
            Wp2[i] = in100 ? f2bf(W2[r * 100 + c]) : (unsigned short)0;
            if (r < 64) {
                LWp[i] = (r < NCLS && c < 100) ? f2bf(LW[r * 100 + c]) : (unsigned short)0;
            }
        }
    }
}

// ---------------------------------------------------------------------------
// scan1: in-place inclusive scan per 1024-block + block totals
// ---------------------------------------------------------------------------
__global__ __launch_bounds__(1024) void scan1_kernel(int* __restrict__ deg,
                                                     int* __restrict__ bsum) {
    __shared__ int wsum[16];
    const int i = blockIdx.x * SCAN_BLK + threadIdx.x;
    const int lane = threadIdx.x & 63;
    const int wid = threadIdx.x >> 6;
    int v = (i < N_NODES_C) ? deg[i] : 0;
    #pragma unroll
    for (int d = 1; d < 64; d <<= 1) {
        int t = __shfl_up(v, d);
        if (lane >= d) v += t;
    }
    if (lane == 63) wsum[wid] = v;
    __syncthreads();
    if (wid == 0) {
        int s = (lane < 16) ? wsum[lane] : 0;
        #pragma unroll
        for (int d = 1; d < 16; d <<= 1) {
            int t = __shfl_up(s, d);
            if (lane >= d) s += t;
        }
        if (lane < 16) wsum[lane] = s;
    }
    __syncthreads();
    if (wid > 0) v += wsum[wid - 1];
    if (i < N_NODES_C) deg[i] = v;
    if (threadIdx.x == SCAN_BLK - 1) bsum[blockIdx.x] = v;
}

// ---------------------------------------------------------------------------
// scan3 (scan2 folded in)
// ---------------------------------------------------------------------------
__global__ __launch_bounds__(1024) void scan3_kernel(const int* __restrict__ incl,
                                                     const int* __restrict__ bsum,
                                                     int* __restrict__ rp,
                                                     int* __restrict__ cursor) {
    __shared__ int boff[SCAN_NBLK];
    if (threadIdx.x < SCAN_NBLK) boff[threadIdx.x] = bsum[threadIdx.x];
    __syncthreads();
    if (threadIdx.x == 0) {
        int off = 0;
        #pragma unroll 1
        for (int j = 0; j < SCAN_NBLK; ++j) { int t = boff[j]; boff[j] = off; off += t; }
    }
    __syncthreads();
    int i = blockIdx.x * SCAN_BLK + threadIdx.x;
    if (i >= N_NODES_C) return;
    int v = incl[i] + boff[blockIdx.x];
    rp[i + 1] = v;
    cursor[i + 1] = v;
    if (i == 0) { rp[0] = 0; cursor[0] = 0; }
}

// ---------------------------------------------------------------------------
// CSR fill, 4-group dst-partitioned (TLP x ILP structure; 4 groups halve
// the re-read tax vs 8). Scale computed inline for in-range edges only.
// csr.x stores src*256 (byte offset into KPAD-stride bf16 arrays).
// ---------------------------------------------------------------------------
__global__ __launch_bounds__(256) void csr_fill_part_kernel(
        const int* __restrict__ node_ids,
        const int* __restrict__ src,
        const int* __restrict__ dst,
        const float* __restrict__ ew,
        const float* __restrict__ alpha,
        int* __restrict__ cursor,
        int2* __restrict__ csr) {
    const int g   = blockIdx.x & (NGRP - 1);
    const int blk = blockIdx.x >> 2;
    const int lo  = g * GRP_NODES;
    const int hi  = lo + GRP_NODES;
    const int base = blk * EDGES_PER_BLK + threadIdx.x * 8;
    #pragma unroll
    for (int half = 0; half < 2; ++half) {
        const int e = base + half * 4;
        if (e >= N_EDGES_C) break;
        int4   s4 = *reinterpret_cast<const int4*>(src + e);
        int4   d4 = *reinterpret_cast<const int4*>(dst + e);
        float4 w4 = *reinterpret_cast<const float4*>(ew + e);
        const int   ss[4] = {s4.x, s4.y, s4.z, s4.w};
        const int   ds[4] = {d4.x, d4.y, d4.z, d4.w};
        const float we[4] = {w4.x, w4.y, w4.z, w4.w};
        #pragma unroll
        for (int i = 0; i < 4; ++i) {
            if (ds[i] >= lo && ds[i] < hi) {
                int sid = node_ids[ss[i]];
                int did = node_ids[ds[i]];
                int idx = GENE + 1;                              // cell-cell
                if (sid >= 0 && did < 0) idx = sid;              // gene -> cell
                else if (did >= 0 && sid < 0) idx = did;         // cell -> gene
                else if (did >= 0 && sid >= 0) idx = GENE;       // gene -> gene
                float sc = alpha[idx] * we[i];
                int pos = atomicAdd(&cursor[ds[i]], 1);
                csr[pos] = make_int2(ss[i] << 8, __float_as_int(sc));
            }
        }
    }
}

// ---------------------------------------------------------------------------
// Aggregation bf16->bf16 (stride KPAD): 2 nodes/wave, 32 lanes each own a
// uint2 (4 bf16 cols), 16-deep clamped unroll (P(deg>16) ~ 0.2% -> almost
// all nodes complete in ONE latency round; clamped dups hit one line).
// f32 accumulate, bf16 padded write. csr.x is a precomputed byte offset.
// ---------------------------------------------------------------------------
__global__ __launch_bounds__(256) void aggregate_kernel(
        const unsigned short* __restrict__ hin,   // [N][KPAD] bf16
        const int* __restrict__ rp,
        const int2* __restrict__ csr,
        unsigned short* __restrict__ nout) {      // [N][KPAD] bf16
    const int node = (blockIdx.x * 256 + threadIdx.x) >> 5;
    const int lane = threadIdx.x & 31;
    const int ll = (lane < 25) ? lane : 24;       // load slot, clamped
    if (node >= N_NODES_C) return;
    const int beg = rp[node];
    const int end = rp[node + 1];
    const char* hb = (const char*)hin;
    float a0 = 0.0f, a1 = 0.0f, a2 = 0.0f, a3 = 0.0f;
    for (int k = beg; k < end; k += 16) {
        uint2 x[16];
        float w[16];
        #pragma unroll
        for (int i = 0; i < 16; ++i) {
            const int kidx = min(k + i, end - 1);
            int2 e = csr[kidx];
            x[i] = ((const uint2*)(hb + (unsigned)e.x))[ll];
            w[i] = (k + i < end) ? __int_as_float(e.y) : 0.0f;
        }
        #pragma unroll
        for (int i = 0; i < 16; ++i) {
            a0 = fmaf(bflo(x[i].x), w[i], a0);
            a1 = fmaf(bfhi(x[i].x), w[i], a1);
            a2 = fmaf(bflo(x[i].y), w[i], a2);
            a3 = fmaf(bfhi(x[i].y), w[i], a3);
        }
    }
    const float invd = (end > beg) ? 1.0f / (float)(end - beg) : 0.0f;
    uint2 o = make_uint2(0u, 0u);
    if (lane < 25) {
        o.x = pack2(a0 * invd, a1 * invd);
        o.y = pack2(a2 * invd, a3 * invd);
    }
    ((uint2*)(nout + (size_t)node * KPAD))[lane] = o;
}

// ---------------------------------------------------------------------------
// MFMA dense: out[m][n] = act( sum_k A[m][k] * W[n][k] + b[n] )
// (round-14 proven, unchanged)
// ---------------------------------------------------------------------------
template <int NOUT, bool RELU, bool OUTBF>
__global__ __launch_bounds__(128) void dense_mfma_kernel(
        const unsigned short* __restrict__ A,     // [N][KPAD] bf16
        const unsigned short* __restrict__ Wp,    // [NT*16][KPAD] bf16
        const float* __restrict__ b,              // [NOUT]
        void* __restrict__ outp) {
    constexpr int NT = (NOUT == 100) ? 7 : 4;     // 16-col tiles

    const int tid = threadIdx.x;
    const int wid = tid >> 6;                     // 0,1
    const int lane = tid & 63;
    const int nl = lane & 15;
    const int kl8 = (lane >> 4) * 8;              // k offset of this lane's frag
    const int n0 = blockIdx.x * 32;
    const int arow = n0 + wid * 16 + nl;          // A row this lane loads

    // acc init = bias (C-in accumulates)
    f32x4 acc[NT];
    #pragma unroll
    for (int t = 0; t < NT; ++t) {
        int n = t * 16 + nl;
        float bt = (n < NOUT) ? b[n] : 0.0f;
        acc[t] = (f32x4){bt, bt, bt, bt};
    }

    const unsigned short* arow_p = A + (size_t)arow * KPAD + kl8;
    #pragma unroll
    for (int kk = 0; kk < 4; ++kk) {
        bf16x8 af = *(const bf16x8*)(arow_p + kk * 32);
        #pragma unroll
        for (int t = 0; t < NT; ++t) {
            bf16x8 bf = *(const bf16x8*)(Wp + (size_t)(t * 16 + nl) * KPAD + kk * 32 + kl8);
            acc[t] = __builtin_amdgcn_mfma_f32_16x16x32_bf16(af, bf, acc[t], 0, 0, 0);
        }
    }

    // Epilogue: D row = (l>>4)*4 + r within band
    const int rbase = n0 + wid * 16 + (lane >> 4) * 4;
    #pragma unroll
    for (int t = 0; t < NT; ++t) {
        const int n = t * 16 + nl;
        #pragma unroll
        for (int r = 0; r < 4; ++r) {
            float v = acc[t][r];
            if (RELU) v = fmaxf(v, 0.0f);
            const int row = rbase + r;
            if (OUTBF) {
                ((unsigned short*)outp)[(size_t)row * KPAD + n] =
                    (n < NOUT) ? f2bf(v) : (unsigned short)0;
            } else {
                if (n < NOUT) ((float*)outp)[(size_t)row * NOUT + n] = v;
            }
        }
    }
    if (OUTBF) {
        // zero pad cols [112,128) for this wave's 16 rows (4 lanes x 8B per row)
        const int zrow = n0 + wid * 16 + (lane >> 2);
        uint2* zp = (uint2*)((unsigned short*)outp + (size_t)zrow * KPAD + 112 + (lane & 3) * 4);
        *zp = make_uint2(0u, 0u);
    }
}

// ---------------------------------------------------------------------------
extern "C" void kernel_launch(void* const* d_in, const int* in_sizes, int n_in,
                              void* d_out, int out_size, void* d_ws, size_t ws_size,
                              hipStream_t stream) {
    const float* features = (const float*)d_in[0];
    const int*   node_ids = (const int*)d_in[1];
    const int*   src      = (const int*)d_in[2];
    const int*   dst      = (const int*)d_in[3];
    const float* ew       = (const float*)d_in[4];
    const float* alpha    = (const float*)d_in[5];
    const float* W1       = (const float*)d_in[6];
    const float* b1       = (const float*)d_in[7];
    const float* W2       = (const float*)d_in[8];
    const float* b2       = (const float*)d_in[9];
    const float* lin_w    = (const float*)d_in[10];
    const float* lin_b    = (const float*)d_in[11];
    float* out = (float*)d_out;

    char* ws = (char*)d_ws;
    size_t off = 0;
    auto alloc = [&](size_t bytes) {
        void* p = ws + off;
        off += (bytes + 255) & ~(size_t)255;
        return p;
    };
    int*   deg    = (int*)alloc((size_t)N_NODES_C * 4);
    int*   bsum   = (int*)alloc((size_t)SCAN_NBLK * 4);
    int*   rp     = (int*)alloc((size_t)(N_NODES_C + 1) * 4);
    int*   cursor = (int*)alloc((size_t)(N_NODES_C + 1) * 4);
    int2*  csr    = (int2*)alloc((size_t)N_EDGES_C * 8);
    unsigned short* fbf     = (unsigned short*)alloc((size_t)N_NODES_C * KPAD * 2);
    unsigned short* h1      = (unsigned short*)alloc((size_t)N_NODES_C * KPAD * 2);
    unsigned short* neigh_b = (unsigned short*)alloc((size_t)N_NODES_C * KPAD * 2);
    unsigned short* Wp1     = (unsigned short*)alloc((size_t)112 * KPAD * 2);
    unsigned short* Wp2     = (unsigned short*)alloc((size_t)112 * KPAD * 2);
    unsigned short* LWp     = (unsigned short*)alloc((size_t)64 * KPAD * 2);
    // h2 aliases fbf: fbf is dead after aggregate-1 reads it.
    unsigned short* h2 = fbf;
    (void)ws_size;

    // --- prep (memset -> fused conversions + partitioned deg count) ---
    hipMemsetAsync(deg, 0, (size_t)N_NODES_C * 4, stream);
    mega_prep_kernel<<<MEGA_BLKS, 256, 0, stream>>>(
        features, dst, W1, W2, lin_w, fbf, deg, Wp1, Wp2, LWp);
    scan1_kernel<<<SCAN_NBLK, SCAN_BLK, 0, stream>>>(deg, bsum);
    scan3_kernel<<<SCAN_NBLK, SCAN_BLK, 0, stream>>>(deg, bsum, rp, cursor);
    csr_fill_part_kernel<<<NGRP * GRP_BLKS, 256, 0, stream>>>(
        node_ids, src, dst, ew, alpha, cursor, csr);

    // --- Layer 1 ---
    aggregate_kernel<<<(N_NODES_C * 32) / 256, 256, 0, stream>>>(fbf, rp, csr, neigh_b);
    dense_mfma_kernel<FEATS, true, true><<<N_NODES_C / 32, 128, 0, stream>>>(
        neigh_b, Wp1, b1, h1);

    // --- Layer 2 ---
    aggregate_kernel<<<(N_NODES_C * 32) / 256, 256, 0, stream>>>(h1, rp, csr, neigh_b);
    dense_mfma_kernel<FEATS, true, true><<<N_NODES_C / 32, 128, 0, stream>>>(
        neigh_b, Wp2, b2, h2);

    // --- Classifier ---
    dense_mfma_kernel<NCLS, false, false><<<N_NODES_C / 32, 128, 0, stream>>>(
        h2, LWp, lin_b, out);
}

// Round 18
// 277.994 us; speedup vs baseline: 1.0621x; 1.0621x over previous
//
#include <hip/hip_runtime.h>

#define N_NODES_C 100000
#define N_EDGES_C 800000
#define FEATS 100
#define NCLS 50
#define GENE 20000
#define SCAN_BLK 1024
#define SCAN_NBLK ((N_NODES_C + SCAN_BLK - 1) / SCAN_BLK)   // 98
#define KPAD 128                                             // padded K (4 x 32)
#define EDGES_PER_BLK 2048
#define GRP_BLKS ((N_EDGES_C + EDGES_PER_BLK - 1) / EDGES_PER_BLK)  // 391 per group
#define NGRP 4
#define GRP_NODES (N_NODES_C / NGRP)                         // 25000
// mega_prep block ranges
#define CONV_BLKS 12500                                      // N*32/256
#define DEG_BLKS (NGRP * GRP_BLKS)                           // 1564
#define WPREP_BLKS 8
#define MEGA_BLKS (CONV_BLKS + DEG_BLKS + WPREP_BLKS)        // 14072

typedef short bf16x8 __attribute__((ext_vector_type(8)));
typedef float f32x4  __attribute__((ext_vector_type(4)));

// bf16 helpers (RNE pack, shift-unpack)
__device__ __forceinline__ unsigned short f2bf(float f) {
    unsigned int x = __float_as_uint(f);
    return (unsigned short)((x + 0x7FFFu + ((x >> 16) & 1u)) >> 16);
}
__device__ __forceinline__ unsigned int pack2(float lo, float hi) {
    return (unsigned int)f2bf(lo) | ((unsigned int)f2bf(hi) << 16);
}
__device__ __forceinline__ float bflo(unsigned int u) { return __uint_as_float(u << 16); }
__device__ __forceinline__ float bfhi(unsigned int u) { return __uint_as_float(u & 0xFFFF0000u); }

// ---------------------------------------------------------------------------
// mega_prep: three independent prep jobs, block-range dispatched.
//   [0, 12500)        : features f32 [N][100] -> bf16 [N][KPAD] (zero-pad)
//   [12500, 14064)    : degree count, 4-group dst-partitioned
//   [14064, 14072)    : pad W1/W2 -> [112][KPAD], lin_w -> [64][KPAD] bf16
// deg is memset to 0 by the preceding stream op.
// ---------------------------------------------------------------------------
__global__ __launch_bounds__(256) void mega_prep_kernel(
        const float* __restrict__ features,
        const int* __restrict__ dst,
        const float* __restrict__ W1,
        const float* __restrict__ W2,
        const float* __restrict__ LW,
        unsigned short* __restrict__ fbf,
        int* __restrict__ deg,
        unsigned short* __restrict__ Wp1,
        unsigned short* __restrict__ Wp2,
        unsigned short* __restrict__ LWp) {
    const int bid = blockIdx.x;
    const int tid = threadIdx.x;

    if (bid < CONV_BLKS) {
        // ---- feature conversion ----
        int i = bid * 256 + tid;                 // < 3.2M exactly
        int node = i >> 5;
        int sl = i & 31;
        uint2 o = make_uint2(0u, 0u);
        if (sl < 25) {
            float4 v = reinterpret_cast<const float4*>(features + (size_t)node * FEATS)[sl];
            o.x = pack2(v.x, v.y);
            o.y = pack2(v.z, v.w);
        }
        reinterpret_cast<uint2*>(fbf + (size_t)node * KPAD)[sl] = o;
    } else if (bid < CONV_BLKS + DEG_BLKS) {
        // ---- degree count, 4-group partitioned ----
        const int b2 = bid - CONV_BLKS;
        const int g   = b2 & (NGRP - 1);
        const int blk = b2 >> 2;
        const int lo  = g * GRP_NODES;
        const int hi  = lo + GRP_NODES;
        const int base = blk * EDGES_PER_BLK + tid * 8;
        #pragma unroll
        for (int half = 0; half < 2; ++half) {
            const int e = base + half * 4;
            if (e >= N_EDGES_C) break;
            int4 d4 = *reinterpret_cast<const int4*>(dst + e);
            const int ds[4] = {d4.x, d4.y, d4.z, d4.w};
            #pragma unroll
            for (int i = 0; i < 4; ++i) {
                if (ds[i] >= lo && ds[i] < hi) atomicAdd(&deg[ds[i]], 1);
            }
        }
    } else {
        // ---- weight pad/convert ----
        const int wb = bid - (CONV_BLKS + DEG_BLKS);
        for (int i = wb * 256 + tid; i < 112 * KPAD; i += WPREP_BLKS * 256) {
            int r = i >> 7;
            int c = i & 127;
            bool in100 = (r < 100) && (c < 100);
            Wp1[i] = in100 ? f2bf(W1[r * 100 + c]) : (unsigned short)0;
            Wp2[i] = in100 ? f2bf(W2[r * 100 + c]) : (unsigned short)0;
            if (r < 64) {
                LWp[i] = (r < NCLS && c < 100) ? f2bf(LW[r * 100 + c]) : (unsigned short)0;
            }
        }
    }
}

// ---------------------------------------------------------------------------
// scan1: in-place inclusive scan per 1024-block + block totals
// ---------------------------------------------------------------------------
__global__ __launch_bounds__(1024) void scan1_kernel(int* __restrict__ deg,
                                                     int* __restrict__ bsum) {
    __shared__ int wsum[16];
    const int i = blockIdx.x * SCAN_BLK + threadIdx.x;
    const int lane = threadIdx.x & 63;
    const int wid = threadIdx.x >> 6;
    int v = (i < N_NODES_C) ? deg[i] : 0;
    #pragma unroll
    for (int d = 1; d < 64; d <<= 1) {
        int t = __shfl_up(v, d);
        if (lane >= d) v += t;
    }
    if (lane == 63) wsum[wid] = v;
    __syncthreads();
    if (wid == 0) {
        int s = (lane < 16) ? wsum[lane] : 0;
        #pragma unroll
        for (int d = 1; d < 16; d <<= 1) {
            int t = __shfl_up(s, d);
            if (lane >= d) s += t;
        }
        if (lane < 16) wsum[lane] = s;
    }
    __syncthreads();
    if (wid > 0) v += wsum[wid - 1];
    if (i < N_NODES_C) deg[i] = v;
    if (threadIdx.x == SCAN_BLK - 1) bsum[blockIdx.x] = v;
}

// ---------------------------------------------------------------------------
// scan3 (scan2 folded in)
// ---------------------------------------------------------------------------
__global__ __launch_bounds__(1024) void scan3_kernel(const int* __restrict__ incl,
                                                     const int* __restrict__ bsum,
                                                     int* __restrict__ rp,
                                                     int* __restrict__ cursor) {
    __shared__ int boff[SCAN_NBLK];
    if (threadIdx.x < SCAN_NBLK) boff[threadIdx.x] = bsum[threadIdx.x];
    __syncthreads();
    if (threadIdx.x == 0) {
        int off = 0;
        #pragma unroll 1
        for (int j = 0; j < SCAN_NBLK; ++j) { int t = boff[j]; boff[j] = off; off += t; }
    }
    __syncthreads();
    int i = blockIdx.x * SCAN_BLK + threadIdx.x;
    if (i >= N_NODES_C) return;
    int v = incl[i] + boff[blockIdx.x];
    rp[i + 1] = v;
    cursor[i + 1] = v;
    if (i == 0) { rp[0] = 0; cursor[0] = 0; }
}

// ---------------------------------------------------------------------------
// CSR fill, 4-group dst-partitioned (TLP x ILP structure). Scale computed
// inline for in-range edges only. csr.x stores src*256 (byte offset).
// ---------------------------------------------------------------------------
__global__ __launch_bounds__(256) void csr_fill_part_kernel(
        const int* __restrict__ node_ids,
        const int* __restrict__ src,
        const int* __restrict__ dst,
        const float* __restrict__ ew,
        const float* __restrict__ alpha,
        int* __restrict__ cursor,
        int2* __restrict__ csr) {
    const int g   = blockIdx.x & (NGRP - 1);
    const int blk = blockIdx.x >> 2;
    const int lo  = g * GRP_NODES;
    const int hi  = lo + GRP_NODES;
    const int base = blk * EDGES_PER_BLK + threadIdx.x * 8;
    #pragma unroll
    for (int half = 0; half < 2; ++half) {
        const int e = base + half * 4;
        if (e >= N_EDGES_C) break;
        int4   s4 = *reinterpret_cast<const int4*>(src + e);
        int4   d4 = *reinterpret_cast<const int4*>(dst + e);
        float4 w4 = *reinterpret_cast<const float4*>(ew + e);
        const int   ss[4] = {s4.x, s4.y, s4.z, s4.w};
        const int   ds[4] = {d4.x, d4.y, d4.z, d4.w};
        const float we[4] = {w4.x, w4.y, w4.z, w4.w};
        #pragma unroll
        for (int i = 0; i < 4; ++i) {
            if (ds[i] >= lo && ds[i] < hi) {
                int sid = node_ids[ss[i]];
                int did = node_ids[ds[i]];
                int idx = GENE + 1;                              // cell-cell
                if (sid >= 0 && did < 0) idx = sid;              // gene -> cell
                else if (did >= 0 && sid < 0) idx = did;         // cell -> gene
                else if (did >= 0 && sid >= 0) idx = GENE;       // gene -> gene
                float sc = alpha[idx] * we[i];
                int pos = atomicAdd(&cursor[ds[i]], 1);
                csr[pos] = make_int2(ss[i] << 8, __float_as_int(sc));
            }
        }
    }
}

// ---------------------------------------------------------------------------
// Aggregation bf16->bf16 (stride KPAD), r16-proven form: 2 nodes/wave,
// 32 lanes each own a uint2 (4 bf16 cols), 8-deep EXPLICIT-SCALAR clamped
// unroll (compiler keeps 8 loads in flight at VGPR 36), f32 accumulate,
// bf16 padded write. csr.x is a precomputed byte offset.
// ---------------------------------------------------------------------------
__global__ __launch_bounds__(256) void aggregate_kernel(
        const unsigned short* __restrict__ hin,   // [N][KPAD] bf16
        const int* __restrict__ rp,
        const int2* __restrict__ csr,
        unsigned short* __restrict__ nout) {      // [N][KPAD] bf16
    const int node = (blockIdx.x * 256 + threadIdx.x) >> 5;
    const int lane = threadIdx.x & 31;
    const int ll = (lane < 25) ? lane : 24;       // load slot, clamped
    if (node >= N_NODES_C) return;
    const int beg = rp[node];
    const int end = rp[node + 1];
    const char* hb = (const char*)hin;
    float a0 = 0.0f, a1 = 0.0f, a2 = 0.0f, a3 = 0.0f;
    for (int k = beg; k < end; k += 8) {
        int kk[8];
        #pragma unroll
        for (int i = 0; i < 8; ++i) kk[i] = min(k + i, end - 1);
        int2 e0 = csr[kk[0]];
        int2 e1 = csr[kk[1]];
        int2 e2 = csr[kk[2]];
        int2 e3 = csr[kk[3]];
        int2 e4 = csr[kk[4]];
        int2 e5 = csr[kk[5]];
        int2 e6 = csr[kk[6]];
        int2 e7 = csr[kk[7]];
        uint2 x0 = ((const uint2*)(hb + (unsigned)e0.x))[ll];
        uint2 x1 = ((const uint2*)(hb + (unsigned)e1.x))[ll];
        uint2 x2 = ((const uint2*)(hb + (unsigned)e2.x))[ll];
        uint2 x3 = ((const uint2*)(hb + (unsigned)e3.x))[ll];
        uint2 x4 = ((const uint2*)(hb + (unsigned)e4.x))[ll];
        uint2 x5 = ((const uint2*)(hb + (unsigned)e5.x))[ll];
        uint2 x6 = ((const uint2*)(hb + (unsigned)e6.x))[ll];
        uint2 x7 = ((const uint2*)(hb + (unsigned)e7.x))[ll];
        float w0 = __int_as_float(e0.y);
        float w1 = (k + 1 < end) ? __int_as_float(e1.y) : 0.0f;
        float w2 = (k + 2 < end) ? __int_as_float(e2.y) : 0.0f;
        float w3 = (k + 3 < end) ? __int_as_float(e3.y) : 0.0f;
        float w4 = (k + 4 < end) ? __int_as_float(e4.y) : 0.0f;
        float w5 = (k + 5 < end) ? __int_as_float(e5.y) : 0.0f;
        float w6 = (k + 6 < end) ? __int_as_float(e6.y) : 0.0f;
        float w7 = (k + 7 < end) ? __int_as_float(e7.y) : 0.0f;
        a0 = fmaf(bflo(x0.x), w0, a0); a1 = fmaf(bfhi(x0.x), w0, a1);
        a2 = fmaf(bflo(x0.y), w0, a2); a3 = fmaf(bfhi(x0.y), w0, a3);
        a0 = fmaf(bflo(x1.x), w1, a0); a1 = fmaf(bfhi(x1.x), w1, a1);
        a2 = fmaf(bflo(x1.y), w1, a2); a3 = fmaf(bfhi(x1.y), w1, a3);
        a0 = fmaf(bflo(x2.x), w2, a0); a1 = fmaf(bfhi(x2.x), w2, a1);
        a2 = fmaf(bflo(x2.y), w2, a2); a3 = fmaf(bfhi(x2.y), w2, a3);
        a0 = fmaf(bflo(x3.x), w3, a0); a1 = fmaf(bfhi(x3.x), w3, a1);
        a2 = fmaf(bflo(x3.y), w3, a2); a3 = fmaf(bfhi(x3.y), w3, a3);
        a0 = fmaf(bflo(x4.x), w4, a0); a1 = fmaf(bfhi(x4.x), w4, a1);
        a2 = fmaf(bflo(x4.y), w4, a2); a3 = fmaf(bfhi(x4.y), w4, a3);
        a0 = fmaf(bflo(x5.x), w5, a0); a1 = fmaf(bfhi(x5.x), w5, a1);
        a2 = fmaf(bflo(x5.y), w5, a2); a3 = fmaf(bfhi(x5.y), w5, a3);
        a0 = fmaf(bflo(x6.x), w6, a0); a1 = fmaf(bfhi(x6.x), w6, a1);
        a2 = fmaf(bflo(x6.y), w6, a2); a3 = fmaf(bfhi(x6.y), w6, a3);
        a0 = fmaf(bflo(x7.x), w7, a0); a1 = fmaf(bfhi(x7.x), w7, a1);
        a2 = fmaf(bflo(x7.y), w7, a2); a3 = fmaf(bfhi(x7.y), w7, a3);
    }
    const float invd = (end > beg) ? 1.0f / (float)(end - beg) : 0.0f;
    uint2 o = make_uint2(0u, 0u);
    if (lane < 25) {
        o.x = pack2(a0 * invd, a1 * invd);
        o.y = pack2(a2 * invd, a3 * invd);
    }
    ((uint2*)(nout + (size_t)node * KPAD))[lane] = o;
}

// ---------------------------------------------------------------------------
// MFMA dense: out[m][n] = act( sum_k A[m][k] * W[n][k] + b[n] )
// (round-14 proven, unchanged)
// ---------------------------------------------------------------------------
template <int NOUT, bool RELU, bool OUTBF>
__global__ __launch_bounds__(128) void dense_mfma_kernel(
        const unsigned short* __restrict__ A,     // [N][KPAD] bf16
        const unsigned short* __restrict__ Wp,    // [NT*16][KPAD] bf16
        const float* __restrict__ b,              // [NOUT]
        void* __restrict__ outp) {
    constexpr int NT = (NOUT == 100) ? 7 : 4;     // 16-col tiles

    const int tid = threadIdx.x;
    const int wid = tid >> 6;                     // 0,1
    const int lane = tid & 63;
    const int nl = lane & 15;
    const int kl8 = (lane >> 4) * 8;              // k offset of this lane's frag
    const int n0 = blockIdx.x * 32;
    const int arow = n0 + wid * 16 + nl;          // A row this lane loads

    // acc init = bias (C-in accumulates)
    f32x4 acc[NT];
    #pragma unroll
    for (int t = 0; t < NT; ++t) {
        int n = t * 16 + nl;
        float bt = (n < NOUT) ? b[n] : 0.0f;
        acc[t] = (f32x4){bt, bt, bt, bt};
    }

    const unsigned short* arow_p = A + (size_t)arow * KPAD + kl8;
    #pragma unroll
    for (int kk = 0; kk < 4; ++kk) {
        bf16x8 af = *(const bf16x8*)(arow_p + kk * 32);
        #pragma unroll
        for (int t = 0; t < NT; ++t) {
            bf16x8 bf = *(const bf16x8*)(Wp + (size_t)(t * 16 + nl) * KPAD + kk * 32 + kl8);
            acc[t] = __builtin_amdgcn_mfma_f32_16x16x32_bf16(af, bf, acc[t], 0, 0, 0);
        }
    }

    // Epilogue: D row = (l>>4)*4 + r within band
    const int rbase = n0 + wid * 16 + (lane >> 4) * 4;
    #pragma unroll
    for (int t = 0; t < NT; ++t) {
        const int n = t * 16 + nl;
        #pragma unroll
        for (int r = 0; r < 4; ++r) {
            float v = acc[t][r];
            if (RELU) v = fmaxf(v, 0.0f);
            const int row = rbase + r;
            if (OUTBF) {
                ((unsigned short*)outp)[(size_t)row * KPAD + n] =
                    (n < NOUT) ? f2bf(v) : (unsigned short)0;
            } else {
                if (n < NOUT) ((float*)outp)[(size_t)row * NOUT + n] = v;
            }
        }
    }
    if (OUTBF) {
        // zero pad cols [112,128) for this wave's 16 rows (4 lanes x 8B per row)
        const int zrow = n0 + wid * 16 + (lane >> 2);
        uint2* zp = (uint2*)((unsigned short*)outp + (size_t)zrow * KPAD + 112 + (lane & 3) * 4);
        *zp = make_uint2(0u, 0u);
    }
}

// ---------------------------------------------------------------------------
extern "C" void kernel_launch(void* const* d_in, const int* in_sizes, int n_in,
                              void* d_out, int out_size, void* d_ws, size_t ws_size,
                              hipStream_t stream) {
    const float* features = (const float*)d_in[0];
    const int*   node_ids = (const int*)d_in[1];
    const int*   src      = (const int*)d_in[2];
    const int*   dst      = (const int*)d_in[3];
    const float* ew       = (const float*)d_in[4];
    const float* alpha    = (const float*)d_in[5];
    const float* W1       = (const float*)d_in[6];
    const float* b1       = (const float*)d_in[7];
    const float* W2       = (const float*)d_in[8];
    const float* b2       = (const float*)d_in[9];
    const float* lin_w    = (const float*)d_in[10];
    const float* lin_b    = (const float*)d_in[11];
    float* out = (float*)d_out;

    char* ws = (char*)d_ws;
    size_t off = 0;
    auto alloc = [&](size_t bytes) {
        void* p = ws + off;
        off += (bytes + 255) & ~(size_t)255;
        return p;
    };
    int*   deg    = (int*)alloc((size_t)N_NODES_C * 4);
    int*   bsum   = (int*)alloc((size_t)SCAN_NBLK * 4);
    int*   rp     = (int*)alloc((size_t)(N_NODES_C + 1) * 4);
    int*   cursor = (int*)alloc((size_t)(N_NODES_C + 1) * 4);
    int2*  csr    = (int2*)alloc((size_t)N_EDGES_C * 8);
    unsigned short* fbf     = (unsigned short*)alloc((size_t)N_NODES_C * KPAD * 2);
    unsigned short* h1      = (unsigned short*)alloc((size_t)N_NODES_C * KPAD * 2);
    unsigned short* neigh_b = (unsigned short*)alloc((size_t)N_NODES_C * KPAD * 2);
    unsigned short* Wp1     = (unsigned short*)alloc((size_t)112 * KPAD * 2);
    unsigned short* Wp2     = (unsigned short*)alloc((size_t)112 * KPAD * 2);
    unsigned short* LWp     = (unsigned short*)alloc((size_t)64 * KPAD * 2);
    // h2 aliases fbf: fbf is dead after aggregate-1 reads it.
    unsigned short* h2 = fbf;
    (void)ws_size;

    // --- prep (memset -> fused conversions + partitioned deg count) ---
    hipMemsetAsync(deg, 0, (size_t)N_NODES_C * 4, stream);
    mega_prep_kernel<<<MEGA_BLKS, 256, 0, stream>>>(
        features, dst, W1, W2, lin_w, fbf, deg, Wp1, Wp2, LWp);
    scan1_kernel<<<SCAN_NBLK, SCAN_BLK, 0, stream>>>(deg, bsum);
    scan3_kernel<<<SCAN_NBLK, SCAN_BLK, 0, stream>>>(deg, bsum, rp, cursor);
    csr_fill_part_kernel<<<NGRP * GRP_BLKS, 256, 0, stream>>>(
        node_ids, src, dst, ew, alpha, cursor, csr);

    // --- Layer 1 ---
    aggregate_kernel<<<(N_NODES_C * 32) / 256, 256, 0, stream>>>(fbf, rp, csr, neigh_b);
    dense_mfma_kernel<FEATS, true, true><<<N_NODES_C / 32, 128, 0, stream>>>(
        neigh_b, Wp1, b1, h1);

    // --- Layer 2 ---
    aggregate_kernel<<<(N_NODES_C * 32) / 256, 256, 0, stream>>>(h1, rp, csr, neigh_b);
    dense_mfma_kernel<FEATS, true, true><<<N_NODES_C / 32, 128, 0, stream>>>(
        neigh_b, Wp2, b2, h2);

    // --- Classifier ---
    dense_mfma_kernel<NCLS, false, false><<<N_NODES_C / 32, 128, 0, stream>>>(
        h2, LWp, lin_b, out);
}

// Round 19
// 270.695 us; speedup vs baseline: 1.0908x; 1.0270x over previous
//
#include <hip/hip_runtime.h>

#define N_NODES_C 100000
#define N_EDGES_C 800000
#define FEATS 100
#define NCLS 50
#define GENE 20000
#define SCAN_BLK 1024
#define SCAN_NBLK ((N_NODES_C + SCAN_BLK - 1) / SCAN_BLK)   // 98
#define KPAD 128                                             // padded K (4 x 32)
#define EDGES_PER_BLK 2048
#define GRP_BLKS ((N_EDGES_C + EDGES_PER_BLK - 1) / EDGES_PER_BLK)  // 391 per group
#define NGRP 4
#define GRP_NODES (N_NODES_C / NGRP)                         // 25000
#define CSR_CAP 1600000                                      // 800K + 8*100K pad bound
// mega_prep block ranges
#define CONV_BLKS 12500                                      // N*32/256
#define DEG_BLKS ((N_EDGES_C + 1023) / 1024)                 // 782 (4 edges/thread)
#define WPREP_BLKS 8
#define MEGA_BLKS (CONV_BLKS + DEG_BLKS + WPREP_BLKS)

typedef short bf16x8 __attribute__((ext_vector_type(8)));
typedef float f32x4  __attribute__((ext_vector_type(4)));

// bf16 helpers (RNE pack, shift-unpack)
__device__ __forceinline__ unsigned short f2bf(float f) {
    unsigned int x = __float_as_uint(f);
    return (unsigned short)((x + 0x7FFFu + ((x >> 16) & 1u)) >> 16);
}
__device__ __forceinline__ unsigned int pack2(float lo, float hi) {
    return (unsigned int)f2bf(lo) | ((unsigned int)f2bf(hi) << 16);
}
__device__ __forceinline__ float bflo(unsigned int u) { return __uint_as_float(u << 16); }
__device__ __forceinline__ float bfhi(unsigned int u) { return __uint_as_float(u & 0xFFFF0000u); }

// ---------------------------------------------------------------------------
// mega_prep: three independent prep jobs, block-range dispatched.
//   [0, CONV)             : features f32 [N][100] -> bf16 [N][KPAD]
//   [CONV, CONV+DEG)      : degree count, unpartitioned 4-edge/thread
//                           (atomic latency hidden by co-resident conv blocks)
//   [CONV+DEG, ...+WPREP) : pad W1/W2 -> [112][KPAD], lin_w -> [64][KPAD]
// deg is memset to 0 by the preceding stream op.
// ---------------------------------------------------------------------------
__global__ __launch_bounds__(256) void mega_prep_kernel(
        const float* __restrict__ features,
        const int* __restrict__ dst,
        const float* __restrict__ W1,
        const float* __restrict__ W2,
        const float* __restrict__ LW,
        unsigned short* __restrict__ fbf,
        int* __restrict__ deg,
        unsigned short* __restrict__ Wp1,
        unsigned short* __restrict__ Wp2,
        unsigned short* __restrict__ LWp) {
    const int bid = blockIdx.x;
    const int tid = threadIdx.x;

    if (bid < CONV_BLKS) {
        // ---- feature conversion ----
        int i = bid * 256 + tid;                 // < 3.2M exactly
        int node = i >> 5;
        int sl = i & 31;
        uint2 o = make_uint2(0u, 0u);
        if (sl < 25) {
            float4 v = reinterpret_cast<const float4*>(features + (size_t)node * FEATS)[sl];
            o.x = pack2(v.x, v.y);
            o.y = pack2(v.z, v.w);
        }
        reinterpret_cast<uint2*>(fbf + (size_t)node * KPAD)[sl] = o;
    } else if (bid < CONV_BLKS + DEG_BLKS) {
        // ---- degree count, unpartitioned, 4 edges/thread ----
        const int e = (bid - CONV_BLKS) * 1024 + tid * 4;
        if (e < N_EDGES_C) {                      // N_EDGES_C % 4 == 0
            int4 d4 = *reinterpret_cast<const int4*>(dst + e);
            atomicAdd(&deg[d4.x], 1);
            atomicAdd(&deg[d4.y], 1);
            atomicAdd(&deg[d4.z], 1);
            atomicAdd(&deg[d4.w], 1);
        }
    } else {
        // ---- weight pad/convert ----
        const int wb = bid - (CONV_BLKS + DEG_BLKS);
        for (int i = wb * 256 + tid; i < 112 * KPAD; i += WPREP_BLKS * 256) {
            int r = i >> 7;
            int c = i & 127;
            bool in100 = (r < 100) && (c < 100);
            Wp1[i] = in100 ? f2bf(W1[r * 100 + c]) : (unsigned short)0;
            Wp2[i] = in100 ? f2bf(W2[r * 100 + c]) : (unsigned short)0;
            if (r < 64) {
                LWp[i] = (r < NCLS && c < 100) ? f2bf(LW[r * 100 + c]) : (unsigned short)0;
            }
        }
    }
}

// ---------------------------------------------------------------------------
// scan1: inclusive scan of pad8(deg) per 1024-block -> sdeg, block totals.
// deg itself is preserved (aggregate needs true degree for inv_deg).
// ---------------------------------------------------------------------------
__global__ __launch_bounds__(1024) void scan1_kernel(const int* __restrict__ deg,
                                                     int* __restrict__ sdeg,
                                                     int* __restrict__ bsum) {
    __shared__ int wsum[16];
    const int i = blockIdx.x * SCAN_BLK + threadIdx.x;
    const int lane = threadIdx.x & 63;
    const int wid = threadIdx.x >> 6;
    int v = (i < N_NODES_C) ? ((deg[i] + 7) & ~7) : 0;   // padded degree
    #pragma unroll
    for (int d = 1; d < 64; d <<= 1) {
        int t = __shfl_up(v, d);
        if (lane >= d) v += t;
    }
    if (lane == 63) wsum[wid] = v;
    __syncthreads();
    if (wid == 0) {
        int s = (lane < 16) ? wsum[lane] : 0;
        #pragma unroll
        for (int d = 1; d < 16; d <<= 1) {
            int t = __shfl_up(s, d);
            if (lane >= d) s += t;
        }
        if (lane < 16) wsum[lane] = s;
    }
    __syncthreads();
    if (wid > 0) v += wsum[wid - 1];
    if (i < N_NODES_C) sdeg[i] = v;
    if (threadIdx.x == SCAN_BLK - 1) bsum[blockIdx.x] = v;
}

// ---------------------------------------------------------------------------
// scan3 (scan2 folded in): rp8 = exclusive padded offsets; cursor copy.
// ---------------------------------------------------------------------------
__global__ __launch_bounds__(1024) void scan3_kernel(const int* __restrict__ sdeg,
                                                     const int* __restrict__ bsum,
                                                     int* __restrict__ rp8,
                                                     int* __restrict__ cursor) {
    __shared__ int boff[SCAN_NBLK];
    if (threadIdx.x < SCAN_NBLK) boff[threadIdx.x] = bsum[threadIdx.x];
    __syncthreads();
    if (threadIdx.x == 0) {
        int off = 0;
        #pragma unroll 1
        for (int j = 0; j < SCAN_NBLK; ++j) { int t = boff[j]; boff[j] = off; off += t; }
    }
    __syncthreads();
    int i = blockIdx.x * SCAN_BLK + threadIdx.x;
    if (i >= N_NODES_C) return;
    int v = sdeg[i] + boff[blockIdx.x];
    rp8[i + 1] = v;
    cursor[i + 1] = v;
    if (i == 0) { rp8[0] = 0; cursor[0] = 0; }
}

// ---------------------------------------------------------------------------
// CSR fill, 4-group dst-partitioned (r18-proven TLP x ILP structure).
// Buckets are padded to x8; csr pre-zeroed so pad entries decode as
// (row 0, weight 0) = exact no-op in the aggregate.
// csr.x stores src*256 (byte offset into KPAD-stride bf16 arrays).
// ---------------------------------------------------------------------------
__global__ __launch_bounds__(256) void csr_fill_part_kernel(
        const int* __restrict__ node_ids,
        const int* __restrict__ src,
        const int* __restrict__ dst,
        const float* __restrict__ ew,
        const float* __restrict__ alpha,
        int* __restrict__ cursor,
        int2* __restrict__ csr) {
    const int g   = blockIdx.x & (NGRP - 1);
    const int blk = blockIdx.x >> 2;
    const int lo  = g * GRP_NODES;
    const int hi  = lo + GRP_NODES;
    const int base = blk * EDGES_PER_BLK + threadIdx.x * 8;
    #pragma unroll
    for (int half = 0; half < 2; ++half) {
        const int e = base + half * 4;
        if (e >= N_EDGES_C) break;
        int4   s4 = *reinterpret_cast<const int4*>(src + e);
        int4   d4 = *reinterpret_cast<const int4*>(dst + e);
        float4 w4 = *reinterpret_cast<const float4*>(ew + e);
        const int   ss[4] = {s4.x, s4.y, s4.z, s4.w};
        const int   ds[4] = {d4.x, d4.y, d4.z, d4.w};
        const float we[4] = {w4.x, w4.y, w4.z, w4.w};
        #pragma unroll
        for (int i = 0; i < 4; ++i) {
            if (ds[i] >= lo && ds[i] < hi) {
                int sid = node_ids[ss[i]];
                int did = node_ids[ds[i]];
                int idx = GENE + 1;                              // cell-cell
                if (sid >= 0 && did < 0) idx = sid;              // gene -> cell
                else if (did >= 0 && sid < 0) idx = did;         // cell -> gene
                else if (did >= 0 && sid >= 0) idx = GENE;       // gene -> gene
                float sc = alpha[idx] * we[i];
                int pos = atomicAdd(&cursor[ds[i]], 1);
                csr[pos] = make_int2(ss[i] << 8, __float_as_int(sc));
            }
        }
    }
}

// ---------------------------------------------------------------------------
// Aggregation bf16->bf16 (stride KPAD): 2 nodes/wave, 32 lanes each own a
// uint2 (4 bf16 cols), 8-deep unroll with NO clamps/selects (buckets are
// zero-padded to x8: pads read row 0 with weight 0 = exact no-op).
// f32 accumulate, bf16 padded write. csr.x is a precomputed byte offset.
// ---------------------------------------------------------------------------
__global__ __launch_bounds__(256) void aggregate_kernel(
        const unsigned short* __restrict__ hin,   // [N][KPAD] bf16
        const int* __restrict__ rp8,
        const int* __restrict__ deg,
        const int2* __restrict__ csr,
        unsigned short* __restrict__ nout) {      // [N][KPAD] bf16
    const int node = (blockIdx.x * 256 + threadIdx.x) >> 5;
    const int lane = threadIdx.x & 31;
    const int ll = (lane < 25) ? lane : 24;       // load slot, clamped
    if (node >= N_NODES_C) return;
    const int beg = rp8[node];
    const int end = rp8[node + 1];                // beg + pad8(deg)
    const char* hb = (const char*)hin;
    float a0 = 0.0f, a1 = 0.0f, a2 = 0.0f, a3 = 0.0f;
    for (int k = beg; k < end; k += 8) {
        int2 e0 = csr[k];
        int2 e1 = csr[k + 1];
        int2 e2 = csr[k + 2];
        int2 e3 = csr[k + 3];
        int2 e4 = csr[k + 4];
        int2 e5 = csr[k + 5];
        int2 e6 = csr[k + 6];
        int2 e7 = csr[k + 7];
        uint2 x0 = ((const uint2*)(hb + (unsigned)e0.x))[ll];
        uint2 x1 = ((const uint2*)(hb + (unsigned)e1.x))[ll];
        uint2 x2 = ((const uint2*)(hb + (unsigned)e2.x))[ll];
        uint2 x3 = ((const uint2*)(hb + (unsigned)e3.x))[ll];
        uint2 x4 = ((const uint2*)(hb + (unsigned)e4.x))[ll];
        uint2 x5 = ((const uint2*)(hb + (unsigned)e5.x))[ll];
        uint2 x6 = ((const uint2*)(hb + (unsigned)e6.x))[ll];
        uint2 x7 = ((const uint2*)(hb + (unsigned)e7.x))[ll];
        float w0 = __int_as_float(e0.y);
        float w1 = __int_as_float(e1.y);
        float w2 = __int_as_float(e2.y);
        float w3 = __int_as_float(e3.y);
        float w4 = __int_as_float(e4.y);
        float w5 = __int_as_float(e5.y);
        float w6 = __int_as_float(e6.y);
        float w7 = __int_as_float(e7.y);
        a0 = fmaf(bflo(x0.x), w0, a0); a1 = fmaf(bfhi(x0.x), w0, a1);
        a2 = fmaf(bflo(x0.y), w0, a2); a3 = fmaf(bfhi(x0.y), w0, a3);
        a0 = fmaf(bflo(x1.x), w1, a0); a1 = fmaf(bfhi(x1.x), w1, a1);
        a2 = fmaf(bflo(x1.y), w1, a2); a3 = fmaf(bfhi(x1.y), w1, a3);
        a0 = fmaf(bflo(x2.x), w2, a0); a1 = fmaf(bfhi(x2.x), w2, a1);
        a2 = fmaf(bflo(x2.y), w2, a2); a3 = fmaf(bfhi(x2.y), w2, a3);
        a0 = fmaf(bflo(x3.x), w3, a0); a1 = fmaf(bfhi(x3.x), w3, a1);
        a2 = fmaf(bflo(x3.y), w3, a2); a3 = fmaf(bfhi(x3.y), w3, a3);
        a0 = fmaf(bflo(x4.x), w4, a0); a1 = fmaf(bfhi(x4.x), w4, a1);
        a2 = fmaf(bflo(x4.y), w4, a2); a3 = fmaf(bfhi(x4.y), w4, a3);
        a0 = fmaf(bflo(x5.x), w5, a0); a1 = fmaf(bfhi(x5.x), w5, a1);
        a2 = fmaf(bflo(x5.y), w5, a2); a3 = fmaf(bfhi(x5.y), w5, a3);
        a0 = fmaf(bflo(x6.x), w6, a0); a1 = fmaf(bfhi(x6.x), w6, a1);
        a2 = fmaf(bflo(x6.y), w6, a2); a3 = fmaf(bfhi(x6.y), w6, a3);
        a0 = fmaf(bflo(x7.x), w7, a0); a1 = fmaf(bfhi(x7.x), w7, a1);
        a2 = fmaf(bflo(x7.y), w7, a2); a3 = fmaf(bfhi(x7.y), w7, a3);
    }
    const int dg = deg[node];
    const float invd = (dg > 0) ? 1.0f / (float)dg : 0.0f;
    uint2 o = make_uint2(0u, 0u);
    if (lane < 25) {
        o.x = pack2(a0 * invd, a1 * invd);
        o.y = pack2(a2 * invd, a3 * invd);
    }
    ((uint2*)(nout + (size_t)node * KPAD))[lane] = o;
}

// ---------------------------------------------------------------------------
// MFMA dense: out[m][n] = act( sum_k A[m][k] * W[n][k] + b[n] )
// (round-14 proven, unchanged)
// ---------------------------------------------------------------------------
template <int NOUT, bool RELU, bool OUTBF>
__global__ __launch_bounds__(128) void dense_mfma_kernel(
        const unsigned short* __restrict__ A,     // [N][KPAD] bf16
        const unsigned short* __restrict__ Wp,    // [NT*16][KPAD] bf16
        const float* __restrict__ b,              // [NOUT]
        void* __restrict__ outp) {
    constexpr int NT = (NOUT == 100) ? 7 : 4;     // 16-col tiles

    const int tid = threadIdx.x;
    const int wid = tid >> 6;                     // 0,1
    const int lane = tid & 63;
    const int nl = lane & 15;
    const int kl8 = (lane >> 4) * 8;              // k offset of this lane's frag
    const int n0 = blockIdx.x * 32;
    const int arow = n0 + wid * 16 + nl;          // A row this lane loads

    // acc init = bias (C-in accumulates)
    f32x4 acc[NT];
    #pragma unroll
    for (int t = 0; t < NT; ++t) {
        int n = t * 16 + nl;
        float bt = (n < NOUT) ? b[n] : 0.0f;
        acc[t] = (f32x4){bt, bt, bt, bt};
    }

    const unsigned short* arow_p = A + (size_t)arow * KPAD + kl8;
    #pragma unroll
    for (int kk = 0; kk < 4; ++kk) {
        bf16x8 af = *(const bf16x8*)(arow_p + kk * 32);
        #pragma unroll
        for (int t = 0; t < NT; ++t) {
            bf16x8 bf = *(const bf16x8*)(Wp + (size_t)(t * 16 + nl) * KPAD + kk * 32 + kl8);
            acc[t] = __builtin_amdgcn_mfma_f32_16x16x32_bf16(af, bf, acc[t], 0, 0, 0);
        }
    }

    // Epilogue: D row = (l>>4)*4 + r within band
    const int rbase = n0 + wid * 16 + (lane >> 4) * 4;
    #pragma unroll
    for (int t = 0; t < NT; ++t) {
        const int n = t * 16 + nl;
        #pragma unroll
        for (int r = 0; r < 4; ++r) {
            float v = acc[t][r];
            if (RELU) v = fmaxf(v, 0.0f);
            const int row = rbase + r;
            if (OUTBF) {
                ((unsigned short*)outp)[(size_t)row * KPAD + n] =
                    (n < NOUT) ? f2bf(v) : (unsigned short)0;
            } else {
                if (n < NOUT) ((float*)outp)[(size_t)row * NOUT + n] = v;
            }
        }
    }
    if (OUTBF) {
        // zero pad cols [112,128) for this wave's 16 rows (4 lanes x 8B per row)
        const int zrow = n0 + wid * 16 + (lane >> 2);
        uint2* zp = (uint2*)((unsigned short*)outp + (size_t)zrow * KPAD + 112 + (lane & 3) * 4);
        *zp = make_uint2(0u, 0u);
    }
}

// ---------------------------------------------------------------------------
extern "C" void kernel_launch(void* const* d_in, const int* in_sizes, int n_in,
                              void* d_out, int out_size, void* d_ws, size_t ws_size,
                              hipStream_t stream) {
    const float* features = (const float*)d_in[0];
    const int*   node_ids = (const int*)d_in[1];
    const int*   src      = (const int*)d_in[2];
    const int*   dst      = (const int*)d_in[3];
    const float* ew       = (const float*)d_in[4];
    const float* alpha    = (const float*)d_in[5];
    const float* W1       = (const float*)d_in[6];
    const float* b1       = (const float*)d_in[7];
    const float* W2       = (const float*)d_in[8];
    const float* b2       = (const float*)d_in[9];
    const float* lin_w    = (const float*)d_in[10];
    const float* lin_b    = (const float*)d_in[11];
    float* out = (float*)d_out;

    char* ws = (char*)d_ws;
    size_t off = 0;
    auto alloc = [&](size_t bytes) {
        void* p = ws + off;
        off += (bytes + 255) & ~(size_t)255;
        return p;
    };
    int*   deg    = (int*)alloc((size_t)N_NODES_C * 4);
    int*   sdeg   = (int*)alloc((size_t)N_NODES_C * 4);
    int*   bsum   = (int*)alloc((size_t)SCAN_NBLK * 4);
    int*   rp8    = (int*)alloc((size_t)(N_NODES_C + 1) * 4);
    int*   cursor = (int*)alloc((size_t)(N_NODES_C + 1) * 4);
    int2*  csr    = (int2*)alloc((size_t)CSR_CAP * 8);
    unsigned short* fbf     = (unsigned short*)alloc((size_t)N_NODES_C * KPAD * 2);
    unsigned short* h1      = (unsigned short*)alloc((size_t)N_NODES_C * KPAD * 2);
    unsigned short* neigh_b = (unsigned short*)alloc((size_t)N_NODES_C * KPAD * 2);
    unsigned short* Wp1     = (unsigned short*)alloc((size_t)112 * KPAD * 2);
    unsigned short* Wp2     = (unsigned short*)alloc((size_t)112 * KPAD * 2);
    unsigned short* LWp     = (unsigned short*)alloc((size_t)64 * KPAD * 2);
    // h2 aliases fbf: fbf is dead after aggregate-1 reads it.
    unsigned short* h2 = fbf;
    (void)ws_size;

    // --- prep (memsets -> fused conversions + deg count) ---
    hipMemsetAsync(deg, 0, (size_t)N_NODES_C * 4, stream);
    hipMemsetAsync(csr, 0, (size_t)CSR_CAP * 8, stream);
    mega_prep_kernel<<<MEGA_BLKS, 256, 0, stream>>>(
        features, dst, W1, W2, lin_w, fbf, deg, Wp1, Wp2, LWp);
    scan1_kernel<<<SCAN_NBLK, SCAN_BLK, 0, stream>>>(deg, sdeg, bsum);
    scan3_kernel<<<SCAN_NBLK, SCAN_BLK, 0, stream>>>(sdeg, bsum, rp8, cursor);
    csr_fill_part_kernel<<<NGRP * GRP_BLKS, 256, 0, stream>>>(
        node_ids, src, dst, ew, alpha, cursor, csr);

    // --- Layer 1 ---
    aggregate_kernel<<<(N_NODES_C * 32) / 256, 256, 0, stream>>>(fbf, rp8, deg, csr, neigh_b);
    dense_mfma_kernel<FEATS, true, true><<<N_NODES_C / 32, 128, 0, stream>>>(
        neigh_b, Wp1, b1, h1);

    // --- Layer 2 ---
    aggregate_kernel<<<(N_NODES_C * 32) / 256, 256, 0, stream>>>(h1, rp8, deg, csr, neigh_b);
    dense_mfma_kernel<FEATS, true, true><<<N_NODES_C / 32, 128, 0, stream>>>(
        neigh_b, Wp2, b2, h2);

    // --- Classifier ---
    dense_mfma_kernel<NCLS, false, false><<<N_NODES_C / 32, 128, 0, stream>>>(
        h2, LWp, lin_b, out);
}

// Round 20
// 260.503 us; speedup vs baseline: 1.1335x; 1.0391x over previous
//
#include <hip/hip_runtime.h>

#define N_NODES_C 100000
#define N_EDGES_C 800000
#define FEATS 100
#define NCLS 50
#define GENE 20000
#define SCAN_BLK 1024
#define SCAN_NBLK ((N_NODES_C + SCAN_BLK - 1) / SCAN_BLK)   // 98
#define KPAD 128                                             // padded K (4 x 32)
#define CSR_CAP 1600000                                      // 800K + 8*100K pad bound
// csr_fill: 2 groups x 4 edges/thread
#define NGRP 2
#define GRP_NODES (N_NODES_C / NGRP)                         // 50000
#define FILL_EPB 1024                                        // 256 thr x 4 edges
#define FILL_BLKS ((N_EDGES_C + FILL_EPB - 1) / FILL_EPB)    // 782
// mega_prep block ranges: deg FIRST (atomics overlap conv streaming)
#define DEG_BLKS ((N_EDGES_C + 1023) / 1024)                 // 782 (4 edges/thread)
#define CONV_SLOTS (N_NODES_C * 32)                          // 3.2M uint2 slots
#define CONV_BLKS ((CONV_SLOTS + 2047) / 2048)               // 1563 (8 slots/thread)
#define WPREP_BLKS 8
#define MEGA_BLKS (DEG_BLKS + CONV_BLKS + WPREP_BLKS)

typedef short bf16x8 __attribute__((ext_vector_type(8)));
typedef float f32x4  __attribute__((ext_vector_type(4)));

// bf16 helpers (RNE pack, shift-unpack)
__device__ __forceinline__ unsigned short f2bf(float f) {
    unsigned int x = __float_as_uint(f);
    return (unsigned short)((x + 0x7FFFu + ((x >> 16) & 1u)) >> 16);
}
__device__ __forceinline__ unsigned int pack2(float lo, float hi) {
    return (unsigned int)f2bf(lo) | ((unsigned int)f2bf(hi) << 16);
}
__device__ __forceinline__ float bflo(unsigned int u) { return __uint_as_float(u << 16); }
__device__ __forceinline__ float bfhi(unsigned int u) { return __uint_as_float(u & 0xFFFF0000u); }

// ---------------------------------------------------------------------------
// mega_prep v2: deg section FIRST so atomic latency hides under the conv
// streaming (grid ~2353 blocks, nearly fully co-resident). Conv section is
// grid-strided x8 (was 1 store/thread at 12500 blocks: launch-rate bound,
// occupancy 28%).
//   [0, DEG)              : degree count, 4 edges/thread, int4 loads
//   [DEG, DEG+CONV)       : features f32 [N][100] -> bf16 [N][KPAD], 8 slots/thr
//   [DEG+CONV, +WPREP)    : pad W1/W2 -> [112][KPAD], lin_w -> [64][KPAD]
// deg is memset to 0 by the preceding stream op.
// ---------------------------------------------------------------------------
__global__ __launch_bounds__(256) void mega_prep_kernel(
        const float* __restrict__ features,
        const int* __restrict__ dst,
        const float* __restrict__ W1,
        const float* __restrict__ W2,
        const float* __restrict__ LW,
        unsigned short* __restrict__ fbf,
        int* __restrict__ deg,
        unsigned short* __restrict__ Wp1,
        unsigned short* __restrict__ Wp2,
        unsigned short* __restrict__ LWp) {
    const int bid = blockIdx.x;
    const int tid = threadIdx.x;

    if (bid < DEG_BLKS) {
        // ---- degree count, 4 edges/thread ----
        const int e = bid * 1024 + tid * 4;
        if (e < N_EDGES_C) {                      // N_EDGES_C % 4 == 0
            int4 d4 = *reinterpret_cast<const int4*>(dst + e);
            atomicAdd(&deg[d4.x], 1);
            atomicAdd(&deg[d4.y], 1);
            atomicAdd(&deg[d4.z], 1);
            atomicAdd(&deg[d4.w], 1);
        }
    } else if (bid < DEG_BLKS + CONV_BLKS) {
        // ---- feature conversion, 8 slots/thread ----
        const int base = (bid - DEG_BLKS) * 2048;
        #pragma unroll
        for (int j = 0; j < 8; ++j) {
            int i = base + j * 256 + tid;
            if (i >= CONV_SLOTS) break;
            int node = i >> 5;
            int sl = i & 31;
            uint2 o = make_uint2(0u, 0u);
            if (sl < 25) {
                float4 v = reinterpret_cast<const float4*>(features + (size_t)node * FEATS)[sl];
                o.x = pack2(v.x, v.y);
                o.y = pack2(v.z, v.w);
            }
            reinterpret_cast<uint2*>(fbf + (size_t)node * KPAD)[sl] = o;
        }
    } else {
        // ---- weight pad/convert ----
        const int wb = bid - (DEG_BLKS + CONV_BLKS);
        for (int i = wb * 256 + tid; i < 112 * KPAD; i += WPREP_BLKS * 256) {
            int r = i >> 7;
            int c = i & 127;
            bool in100 = (r < 100) && (c < 100);
            Wp1[i] = in100 ? f2bf(W1[r * 100 + c]) : (unsigned short)0;
            Wp2[i] = in100 ? f2bf(W2[r * 100 + c]) : (unsigned short)0;
            if (r < 64) {
                LWp[i] = (r < NCLS && c < 100) ? f2bf(LW[r * 100 + c]) : (unsigned short)0;
            }
        }
    }
}

// ---------------------------------------------------------------------------
// scan1: inclusive scan of pad8(deg) per 1024-block -> sdeg, block totals.
// deg itself is preserved (csr_fill needs true degree for inv_deg).
// ---------------------------------------------------------------------------
__global__ __launch_bounds__(1024) void scan1_kernel(const int* __restrict__ deg,
                                                     int* __restrict__ sdeg,
                                                     int* __restrict__ bsum) {
    __shared__ int wsum[16];
    const int i = blockIdx.x * SCAN_BLK + threadIdx.x;
    const int lane = threadIdx.x & 63;
    const int wid = threadIdx.x >> 6;
    int v = (i < N_NODES_C) ? ((deg[i] + 7) & ~7) : 0;   // padded degree
    #pragma unroll
    for (int d = 1; d < 64; d <<= 1) {
        int t = __shfl_up(v, d);
        if (lane >= d) v += t;
    }
    if (lane == 63) wsum[wid] = v;
    __syncthreads();
    if (wid == 0) {
        int s = (lane < 16) ? wsum[lane] : 0;
        #pragma unroll
        for (int d = 1; d < 16; d <<= 1) {
            int t = __shfl_up(s, d);
            if (lane >= d) s += t;
        }
        if (lane < 16) wsum[lane] = s;
    }
    __syncthreads();
    if (wid > 0) v += wsum[wid - 1];
    if (i < N_NODES_C) sdeg[i] = v;
    if (threadIdx.x == SCAN_BLK - 1) bsum[blockIdx.x] = v;
}

// ---------------------------------------------------------------------------
// scan3 (scan2 folded in): rp8 = exclusive padded offsets; cursor copy.
// ---------------------------------------------------------------------------
__global__ __launch_bounds__(1024) void scan3_kernel(const int* __restrict__ sdeg,
                                                     const int* __restrict__ bsum,
                                                     int* __restrict__ rp8,
                                                     int* __restrict__ cursor) {
    __shared__ int boff[SCAN_NBLK];
    if (threadIdx.x < SCAN_NBLK) boff[threadIdx.x] = bsum[threadIdx.x];
    __syncthreads();
    if (threadIdx.x == 0) {
        int off = 0;
        #pragma unroll 1
        for (int j = 0; j < SCAN_NBLK; ++j) { int t = boff[j]; boff[j] = off; off += t; }
    }
    __syncthreads();
    int i = blockIdx.x * SCAN_BLK + threadIdx.x;
    if (i >= N_NODES_C) return;
    int v = sdeg[i] + boff[blockIdx.x];
    rp8[i + 1] = v;
    cursor[i + 1] = v;
    if (i == 0) { rp8[0] = 0; cursor[0] = 0; }
}

// ---------------------------------------------------------------------------
// CSR fill, 2-group dst-partitioned, 4 edges/thread (1564 blocks: same TLP
// as r18's 4-group form, half the re-read tax). inv_deg is FOLDED into the
// stored scale (deg is final before this kernel) -> aggregate needs no deg.
// Buckets padded to x8; csr pre-zeroed so pads decode as (row 0, weight 0).
// csr.x stores src*256 (byte offset into KPAD-stride bf16 arrays).
// ---------------------------------------------------------------------------
__global__ __launch_bounds__(256) void csr_fill_part_kernel(
        const int* __restrict__ node_ids,
        const int* __restrict__ src,
        const int* __restrict__ dst,
        const float* __restrict__ ew,
        const float* __restrict__ alpha,
        const int* __restrict__ deg,
        int* __restrict__ cursor,
        int2* __restrict__ csr) {
    const int g   = blockIdx.x & (NGRP - 1);
    const int blk = blockIdx.x >> 1;
    const int lo  = g * GRP_NODES;
    const int hi  = lo + GRP_NODES;
    const int e = blk * FILL_EPB + threadIdx.x * 4;
    if (e >= N_EDGES_C) return;                   // N_EDGES_C % 4 == 0
    int4   s4 = *reinterpret_cast<const int4*>(src + e);
    int4   d4 = *reinterpret_cast<const int4*>(dst + e);
    float4 w4 = *reinterpret_cast<const float4*>(ew + e);
    const int   ss[4] = {s4.x, s4.y, s4.z, s4.w};
    const int   ds[4] = {d4.x, d4.y, d4.z, d4.w};
    const float we[4] = {w4.x, w4.y, w4.z, w4.w};
    #pragma unroll
    for (int i = 0; i < 4; ++i) {
        if (ds[i] >= lo && ds[i] < hi) {
            int sid = node_ids[ss[i]];
            int did = node_ids[ds[i]];
            int idx = GENE + 1;                              // cell-cell
            if (sid >= 0 && did < 0) idx = sid;              // gene -> cell
            else if (did >= 0 && sid < 0) idx = did;         // cell -> gene
            else if (did >= 0 && sid >= 0) idx = GENE;       // gene -> gene
            float invd = 1.0f / (float)deg[ds[i]];           // deg >= 1 here
            float sc = alpha[idx] * we[i] * invd;
            int pos = atomicAdd(&cursor[ds[i]], 1);
            csr[pos] = make_int2(ss[i] << 8, __float_as_int(sc));
        }
    }
}

// ---------------------------------------------------------------------------
// Aggregation bf16->bf16 (stride KPAD): 2 nodes/wave, 32 lanes each own a
// uint2 (4 bf16 cols), 8-deep unroll, NO clamps/selects (zero-padded x8
// buckets) and NO inv_deg pass (folded into scale at fill time).
// csr.x is a precomputed byte offset.
// ---------------------------------------------------------------------------
__global__ __launch_bounds__(256) void aggregate_kernel(
        const unsigned short* __restrict__ hin,   // [N][KPAD] bf16
        const int* __restrict__ rp8,
        const int2* __restrict__ csr,
        unsigned short* __restrict__ nout) {      // [N][KPAD] bf16
    const int node = (blockIdx.x * 256 + threadIdx.x) >> 5;
    const int lane = threadIdx.x & 31;
    const int ll = (lane < 25) ? lane : 24;       // load slot, clamped
    if (node >= N_NODES_C) return;
    const int beg = rp8[node];
    const int end = rp8[node + 1];                // beg + pad8(deg)
    const char* hb = (const char*)hin;
    float a0 = 0.0f, a1 = 0.0f, a2 = 0.0f, a3 = 0.0f;
    for (int k = beg; k < end; k += 8) {
        int2 e0 = csr[k];
        int2 e1 = csr[k + 1];
        int2 e2 = csr[k + 2];
        int2 e3 = csr[k + 3];
        int2 e4 = csr[k + 4];
        int2 e5 = csr[k + 5];
        int2 e6 = csr[k + 6];
        int2 e7 = csr[k + 7];
        uint2 x0 = ((const uint2*)(hb + (unsigned)e0.x))[ll];
        uint2 x1 = ((const uint2*)(hb + (unsigned)e1.x))[ll];
        uint2 x2 = ((const uint2*)(hb + (unsigned)e2.x))[ll];
        uint2 x3 = ((const uint2*)(hb + (unsigned)e3.x))[ll];
        uint2 x4 = ((const uint2*)(hb + (unsigned)e4.x))[ll];
        uint2 x5 = ((const uint2*)(hb + (unsigned)e5.x))[ll];
        uint2 x6 = ((const uint2*)(hb + (unsigned)e6.x))[ll];
        uint2 x7 = ((const uint2*)(hb + (unsigned)e7.x))[ll];
        float w0 = __int_as_float(e0.y);
        float w1 = __int_as_float(e1.y);
        float w2 = __int_as_float(e2.y);
        float w3 = __int_as_float(e3.y);
        float w4 = __int_as_float(e4.y);
        float w5 = __int_as_float(e5.y);
        float w6 = __int_as_float(e6.y);
        float w7 = __int_as_float(e7.y);
        a0 = fmaf(bflo(x0.x), w0, a0); a1 = fmaf(bfhi(x0.x), w0, a1);
        a2 = fmaf(bflo(x0.y), w0, a2); a3 = fmaf(bfhi(x0.y), w0, a3);
        a0 = fmaf(bflo(x1.x), w1, a0); a1 = fmaf(bfhi(x1.x), w1, a1);
        a2 = fmaf(bflo(x1.y), w1, a2); a3 = fmaf(bfhi(x1.y), w1, a3);
        a0 = fmaf(bflo(x2.x), w2, a0); a1 = fmaf(bfhi(x2.x), w2, a1);
        a2 = fmaf(bflo(x2.y), w2, a2); a3 = fmaf(bfhi(x2.y), w2, a3);
        a0 = fmaf(bflo(x3.x), w3, a0); a1 = fmaf(bfhi(x3.x), w3, a1);
        a2 = fmaf(bflo(x3.y), w3, a2); a3 = fmaf(bfhi(x3.y), w3, a3);
        a0 = fmaf(bflo(x4.x), w4, a0); a1 = fmaf(bfhi(x4.x), w4, a1);
        a2 = fmaf(bflo(x4.y), w4, a2); a3 = fmaf(bfhi(x4.y), w4, a3);
        a0 = fmaf(bflo(x5.x), w5, a0); a1 = fmaf(bfhi(x5.x), w5, a1);
        a2 = fmaf(bflo(x5.y), w5, a2); a3 = fmaf(bfhi(x5.y), w5, a3);
        a0 = fmaf(bflo(x6.x), w6, a0); a1 = fmaf(bfhi(x6.x), w6, a1);
        a2 = fmaf(bflo(x6.y), w6, a2); a3 = fmaf(bfhi(x6.y), w6, a3);
        a0 = fmaf(bflo(x7.x), w7, a0); a1 = fmaf(bfhi(x7.x), w7, a1);
        a2 = fmaf(bflo(x7.y), w7, a2); a3 = fmaf(bfhi(x7.y), w7, a3);
    }
    uint2 o = make_uint2(0u, 0u);
    if (lane < 25) {
        o.x = pack2(a0, a1);
        o.y = pack2(a2, a3);
    }
    ((uint2*)(nout + (size_t)node * KPAD))[lane] = o;
}

// ---------------------------------------------------------------------------
// MFMA dense: out[m][n] = act( sum_k A[m][k] * W[n][k] + b[n] )
// (round-14 proven, unchanged)
// ---------------------------------------------------------------------------
template <int NOUT, bool RELU, bool OUTBF>
__global__ __launch_bounds__(128) void dense_mfma_kernel(
        const unsigned short* __restrict__ A,     // [N][KPAD] bf16
        const unsigned short* __restrict__ Wp,    // [NT*16][KPAD] bf16
        const float* __restrict__ b,              // [NOUT]
        void* __restrict__ outp) {
    constexpr int NT = (NOUT == 100) ? 7 : 4;     // 16-col tiles

    const int tid = threadIdx.x;
    const int wid = tid >> 6;                     // 0,1
    const int lane = tid & 63;
    const int nl = lane & 15;
    const int kl8 = (lane >> 4) * 8;              // k offset of this lane's frag
    const int n0 = blockIdx.x * 32;
    const int arow = n0 + wid * 16 + nl;          // A row this lane loads

    // acc init = bias (C-in accumulates)
    f32x4 acc[NT];
    #pragma unroll
    for (int t = 0; t < NT; ++t) {
        int n = t * 16 + nl;
        float bt = (n < NOUT) ? b[n] : 0.0f;
        acc[t] = (f32x4){bt, bt, bt, bt};
    }

    const unsigned short* arow_p = A + (size_t)arow * KPAD + kl8;
    #pragma unroll
    for (int kk = 0; kk < 4; ++kk) {
        bf16x8 af = *(const bf16x8*)(arow_p + kk * 32);
        #pragma unroll
        for (int t = 0; t < NT; ++t) {
            bf16x8 bf = *(const bf16x8*)(Wp + (size_t)(t * 16 + nl) * KPAD + kk * 32 + kl8);
            acc[t] = __builtin_amdgcn_mfma_f32_16x16x32_bf16(af, bf, acc[t], 0, 0, 0);
        }
    }

    // Epilogue: D row = (l>>4)*4 + r within band
    const int rbase = n0 + wid * 16 + (lane >> 4) * 4;
    #pragma unroll
    for (int t = 0; t < NT; ++t) {
        const int n = t * 16 + nl;
        #pragma unroll
        for (int r = 0; r < 4; ++r) {
            float v = acc[t][r];
            if (RELU) v = fmaxf(v, 0.0f);
            const int row = rbase + r;
            if (OUTBF) {
                ((unsigned short*)outp)[(size_t)row * KPAD + n] =
                    (n < NOUT) ? f2bf(v) : (unsigned short)0;
            } else {
                if (n < NOUT) ((float*)outp)[(size_t)row * NOUT + n] = v;
            }
        }
    }
    if (OUTBF) {
        // zero pad cols [112,128) for this wave's 16 rows (4 lanes x 8B per row)
        const int zrow = n0 + wid * 16 + (lane >> 2);
        uint2* zp = (uint2*)((unsigned short*)outp + (size_t)zrow * KPAD + 112 + (lane & 3) * 4);
        *zp = make_uint2(0u, 0u);
    }
}

// ---------------------------------------------------------------------------
extern "C" void kernel_launch(void* const* d_in, const int* in_sizes, int n_in,
                              void* d_out, int out_size, void* d_ws, size_t ws_size,
                              hipStream_t stream) {
    const float* features = (const float*)d_in[0];
    const int*   node_ids = (const int*)d_in[1];
    const int*   src      = (const int*)d_in[2];
    const int*   dst      = (const int*)d_in[3];
    const float* ew       = (const float*)d_in[4];
    const float* alpha    = (const float*)d_in[5];
    const float* W1       = (const float*)d_in[6];
    const float* b1       = (const float*)d_in[7];
    const float* W2       = (const float*)d_in[8];
    const float* b2       = (const float*)d_in[9];
    const float* lin_w    = (const float*)d_in[10];
    const float* lin_b    = (const float*)d_in[11];
    float* out = (float*)d_out;

    char* ws = (char*)d_ws;
    size_t off = 0;
    auto alloc = [&](size_t bytes) {
        void* p = ws + off;
        off += (bytes + 255) & ~(size_t)255;
        return p;
    };
    int*   deg    = (int*)alloc((size_t)N_NODES_C * 4);
    int*   sdeg   = (int*)alloc((size_t)N_NODES_C * 4);
    int*   bsum   = (int*)alloc((size_t)SCAN_NBLK * 4);
    int*   rp8    = (int*)alloc((size_t)(N_NODES_C + 1) * 4);
    int*   cursor = (int*)alloc((size_t)(N_NODES_C + 1) * 4);
    int2*  csr    = (int2*)alloc((size_t)CSR_CAP * 8);
    unsigned short* fbf     = (unsigned short*)alloc((size_t)N_NODES_C * KPAD * 2);
    unsigned short* h1      = (unsigned short*)alloc((size_t)N_NODES_C * KPAD * 2);
    unsigned short* neigh_b = (unsigned short*)alloc((size_t)N_NODES_C * KPAD * 2);
    unsigned short* Wp1     = (unsigned short*)alloc((size_t)112 * KPAD * 2);
    unsigned short* Wp2     = (unsigned short*)alloc((size_t)112 * KPAD * 2);
    unsigned short* LWp     = (unsigned short*)alloc((size_t)64 * KPAD * 2);
    // h2 aliases fbf: fbf is dead after aggregate-1 reads it.
    unsigned short* h2 = fbf;
    (void)ws_size;

    // --- prep (memsets -> fused deg count + conversions) ---
    hipMemsetAsync(deg, 0, (size_t)N_NODES_C * 4, stream);
    hipMemsetAsync(csr, 0, (size_t)CSR_CAP * 8, stream);
    mega_prep_kernel<<<MEGA_BLKS, 256, 0, stream>>>(
        features, dst, W1, W2, lin_w, fbf, deg, Wp1, Wp2, LWp);
    scan1_kernel<<<SCAN_NBLK, SCAN_BLK, 0, stream>>>(deg, sdeg, bsum);
    scan3_kernel<<<SCAN_NBLK, SCAN_BLK, 0, stream>>>(sdeg, bsum, rp8, cursor);
    csr_fill_part_kernel<<<NGRP * FILL_BLKS, 256, 0, stream>>>(
        node_ids, src, dst, ew, alpha, deg, cursor, csr);

    // --- Layer 1 ---
    aggregate_kernel<<<(N_NODES_C * 32) / 256, 256, 0, stream>>>(fbf, rp8, csr, neigh_b);
    dense_mfma_kernel<FEATS, true, true><<<N_NODES_C / 32, 128, 0, stream>>>(
        neigh_b, Wp1, b1, h1);

    // --- Layer 2 ---
    aggregate_kernel<<<(N_NODES_C * 32) / 256, 256, 0, stream>>>(h1, rp8, csr, neigh_b);
    dense_mfma_kernel<FEATS, true, true><<<N_NODES_C / 32, 128, 0, stream>>>(
        neigh_b, Wp2, b2, h2);

    // --- Classifier ---
    dense_mfma_kernel<NCLS, false, false><<<N_NODES_C / 32, 128, 0, stream>>>(
        h2, LWp, lin_b, out);
}

// Round 21
// 239.152 us; speedup vs baseline: 1.2347x; 1.0893x over previous
//
#include <hip/hip_runtime.h>

#define N_NODES_C 100000
#define N_EDGES_C 800000
#define FEATS 100
#define NCLS 50
#define GENE 20000
#define SCAN_BLK 1024
#define SCAN_NBLK ((N_NODES_C + SCAN_BLK - 1) / SCAN_BLK)   // 98
#define KPAD 128                                             // padded K (4 x 32)
#define CSR_CAP 1600000                                      // 800K + 8*100K pad bound
// edge-parallel kernels: 4 edges/thread, 256 threads
#define EDGE_BLKS ((N_EDGES_C + 1023) / 1024)                // 782
// mega_prep block ranges: edge section FIRST (atomic pole), conv fills around
#define CONV_SLOTS (N_NODES_C * 32)                          // 3.2M uint2 slots
#define CONV_BLKS ((CONV_SLOTS + 2047) / 2048)               // 1563 (8 slots/thread)
#define WPREP_BLKS 8
#define MEGA_BLKS (EDGE_BLKS + CONV_BLKS + WPREP_BLKS)

typedef short bf16x8 __attribute__((ext_vector_type(8)));
typedef float f32x4  __attribute__((ext_vector_type(4)));

// bf16 helpers (RNE pack, shift-unpack)
__device__ __forceinline__ unsigned short f2bf(float f) {
    unsigned int x = __float_as_uint(f);
    return (unsigned short)((x + 0x7FFFu + ((x >> 16) & 1u)) >> 16);
}
__device__ __forceinline__ unsigned int pack2(float lo, float hi) {
    return (unsigned int)f2bf(lo) | ((unsigned int)f2bf(hi) << 16);
}
__device__ __forceinline__ float bflo(unsigned int u) { return __uint_as_float(u << 16); }
__device__ __forceinline__ float bfhi(unsigned int u) { return __uint_as_float(u & 0xFFFF0000u); }

// ---------------------------------------------------------------------------
// mega_prep v3: the SINGLE atomic pass + conversions, block-range dispatched.
//   [0, EDGE)           : per edge: scale_noinv = alpha[idx]*ew,
//                         pos = atomicAdd(&cnt[dst],1), staging[e]=(pos,scale)
//                         (coalesced 32B/thread staging write). cnt doubles
//                         as deg. This replaces BOTH former atomic passes.
//   [EDGE, EDGE+CONV)   : features f32 [N][100] -> bf16 [N][KPAD], 8 slots/thr
//   [EDGE+CONV, +WPREP) : pad W1/W2 -> [112][KPAD], lin_w -> [64][KPAD]
// cnt is memset to 0 by the preceding stream op.
// ---------------------------------------------------------------------------
__global__ __launch_bounds__(256) void mega_prep_kernel(
        const float* __restrict__ features,
        const int* __restrict__ node_ids,
        const int* __restrict__ src,
        const int* __restrict__ dst,
        const float* __restrict__ ew,
        const float* __restrict__ alpha,
        unsigned short* __restrict__ fbf,
        int* __restrict__ cnt,
        int2* __restrict__ staging,
        const float* __restrict__ W1,
        const float* __restrict__ W2,
        const float* __restrict__ LW,
        unsigned short* __restrict__ Wp1,
        unsigned short* __restrict__ Wp2,
        unsigned short* __restrict__ LWp) {
    const int bid = blockIdx.x;
    const int tid = threadIdx.x;

    if (bid < EDGE_BLKS) {
        // ---- single atomic pass: count + scale + staging ----
        const int e = bid * 1024 + tid * 4;
        if (e < N_EDGES_C) {                      // N_EDGES_C % 4 == 0
            int4   s4 = *reinterpret_cast<const int4*>(src + e);
            int4   d4 = *reinterpret_cast<const int4*>(dst + e);
            float4 w4 = *reinterpret_cast<const float4*>(ew + e);
            const int   ss[4] = {s4.x, s4.y, s4.z, s4.w};
            const int   ds[4] = {d4.x, d4.y, d4.z, d4.w};
            const float we[4] = {w4.x, w4.y, w4.z, w4.w};
            int sid[4], did[4];
            #pragma unroll
            for (int i = 0; i < 4; ++i) sid[i] = node_ids[ss[i]];
            #pragma unroll
            for (int i = 0; i < 4; ++i) did[i] = node_ids[ds[i]];
            int pos[4];
            float sc[4];
            #pragma unroll
            for (int i = 0; i < 4; ++i) {
                int idx = GENE + 1;                              // cell-cell
                if (sid[i] >= 0 && did[i] < 0) idx = sid[i];     // gene -> cell
                else if (did[i] >= 0 && sid[i] < 0) idx = did[i];// cell -> gene
                else if (did[i] >= 0 && sid[i] >= 0) idx = GENE; // gene -> gene
                sc[i] = alpha[idx] * we[i];
                pos[i] = atomicAdd(&cnt[ds[i]], 1);
            }
            int4 st01 = make_int4(pos[0], __float_as_int(sc[0]),
                                  pos[1], __float_as_int(sc[1]));
            int4 st23 = make_int4(pos[2], __float_as_int(sc[2]),
                                  pos[3], __float_as_int(sc[3]));
            reinterpret_cast<int4*>(staging)[(e >> 1)]     = st01;
            reinterpret_cast<int4*>(staging)[(e >> 1) + 1] = st23;
        }
    } else if (bid < EDGE_BLKS + CONV_BLKS) {
        // ---- feature conversion, 8 slots/thread ----
        const int base = (bid - EDGE_BLKS) * 2048;
        #pragma unroll
        for (int j = 0; j < 8; ++j) {
            int i = base + j * 256 + tid;
            if (i >= CONV_SLOTS) break;
            int node = i >> 5;
            int sl = i & 31;
            uint2 o = make_uint2(0u, 0u);
            if (sl < 25) {
                float4 v = reinterpret_cast<const float4*>(features + (size_t)node * FEATS)[sl];
                o.x = pack2(v.x, v.y);
                o.y = pack2(v.z, v.w);
            }
            reinterpret_cast<uint2*>(fbf + (size_t)node * KPAD)[sl] = o;
        }
    } else {
        // ---- weight pad/convert ----
        const int wb = bid - (EDGE_BLKS + CONV_BLKS);
        for (int i = wb * 256 + tid; i < 112 * KPAD; i += WPREP_BLKS * 256) {
            int r = i >> 7;
            int c = i & 127;
            bool in100 = (r < 100) && (c < 100);
            Wp1[i] = in100 ? f2bf(W1[r * 100 + c]) : (unsigned short)0;
            Wp2[i] = in100 ? f2bf(W2[r * 100 + c]) : (unsigned short)0;
            if (r < 64) {
                LWp[i] = (r < NCLS && c < 100) ? f2bf(LW[r * 100 + c]) : (unsigned short)0;
            }
        }
    }
}

// ---------------------------------------------------------------------------
// scan1: inclusive scan of pad8(cnt) per 1024-block -> sdeg, block totals.
// cnt itself is preserved (scan3 derives inv_deg from it).
// ---------------------------------------------------------------------------
__global__ __launch_bounds__(1024) void scan1_kernel(const int* __restrict__ cnt,
                                                     int* __restrict__ sdeg,
                                                     int* __restrict__ bsum) {
    __shared__ int wsum[16];
    const int i = blockIdx.x * SCAN_BLK + threadIdx.x;
    const int lane = threadIdx.x & 63;
    const int wid = threadIdx.x >> 6;
    int v = (i < N_NODES_C) ? ((cnt[i] + 7) & ~7) : 0;   // padded degree
    #pragma unroll
    for (int d = 1; d < 64; d <<= 1) {
        int t = __shfl_up(v, d);
        if (lane >= d) v += t;
    }
    if (lane == 63) wsum[wid] = v;
    __syncthreads();
    if (wid == 0) {
        int s = (lane < 16) ? wsum[lane] : 0;
        #pragma unroll
        for (int d = 1; d < 16; d <<= 1) {
            int t = __shfl_up(s, d);
            if (lane >= d) s += t;
        }
        if (lane < 16) wsum[lane] = s;
    }
    __syncthreads();
    if (wid > 0) v += wsum[wid - 1];
    if (i < N_NODES_C) sdeg[i] = v;
    if (threadIdx.x == SCAN_BLK - 1) bsum[blockIdx.x] = v;
}

// ---------------------------------------------------------------------------
// scan3 (scan2 folded in): rp8 = exclusive padded offsets (for aggregate);
// rpc[node] = (bucket_start, inv_deg as float bits) for placement (1 gather).
// ---------------------------------------------------------------------------
__global__ __launch_bounds__(1024) void scan3_kernel(const int* __restrict__ sdeg,
                                                     const int* __restrict__ bsum,
                                                     const int* __restrict__ cnt,
                                                     int* __restrict__ rp8,
                                                     int2* __restrict__ rpc) {
    __shared__ int boff[SCAN_NBLK];
    if (threadIdx.x < SCAN_NBLK) boff[threadIdx.x] = bsum[threadIdx.x];
    __syncthreads();
    if (threadIdx.x == 0) {
        int off = 0;
        #pragma unroll 1
        for (int j = 0; j < SCAN_NBLK; ++j) { int t = boff[j]; boff[j] = off; off += t; }
    }
    __syncthreads();
    int i = blockIdx.x * SCAN_BLK + threadIdx.x;
    if (i >= N_NODES_C) return;
    int v = sdeg[i] + boff[blockIdx.x];           // inclusive padded sum
    rp8[i + 1] = v;
    int dg = cnt[i];
    int pd = (dg + 7) & ~7;
    float invd = (dg > 0) ? 1.0f / (float)dg : 0.0f;
    rpc[i] = make_int2(v - pd, __float_as_int(invd));
    if (i == 0) rp8[0] = 0;
}

// ---------------------------------------------------------------------------
// Placement: NO atomics. Streaming reads (src, dst, staging), one rpc
// gather per edge, scatter csr[start + pos] = (src*256, scale*inv_deg).
// Buckets padded to x8; csr pre-zeroed so pads decode as (row 0, weight 0).
// ---------------------------------------------------------------------------
__global__ __launch_bounds__(256) void placement_kernel(
        const int* __restrict__ src,
        const int* __restrict__ dst,
        const int2* __restrict__ staging,
        const int2* __restrict__ rpc,
        int2* __restrict__ csr) {
    const int e = blockIdx.x * 1024 + threadIdx.x * 4;
    if (e >= N_EDGES_C) return;                   // N_EDGES_C % 4 == 0
    int4 s4 = *reinterpret_cast<const int4*>(src + e);
    int4 d4 = *reinterpret_cast<const int4*>(dst + e);
    int4 st01 = reinterpret_cast<const int4*>(staging)[(e >> 1)];
    int4 st23 = reinterpret_cast<const int4*>(staging)[(e >> 1) + 1];
    const int   ss[4]  = {s4.x, s4.y, s4.z, s4.w};
    const int   ds[4]  = {d4.x, d4.y, d4.z, d4.w};
    const int   pos[4] = {st01.x, st01.z, st23.x, st23.z};
    const float sc[4]  = {__int_as_float(st01.y), __int_as_float(st01.w),
                          __int_as_float(st23.y), __int_as_float(st23.w)};
    #pragma unroll
    for (int i = 0; i < 4; ++i) {
        int2 rc = rpc[ds[i]];
        float v = sc[i] * __int_as_float(rc.y);
        csr[rc.x + pos[i]] = make_int2(ss[i] << 8, __float_as_int(v));
    }
}

// ---------------------------------------------------------------------------
// Aggregation bf16->bf16 (stride KPAD): 2 nodes/wave, 32 lanes each own a
// uint2 (4 bf16 cols), 8-deep unroll, NO clamps/selects (zero-padded x8
// buckets), inv_deg folded into scale. csr.x is a precomputed byte offset.
// (r20-proven, unchanged)
// ---------------------------------------------------------------------------
__global__ __launch_bounds__(256) void aggregate_kernel(
        const unsigned short* __restrict__ hin,   // [N][KPAD] bf16
        const int* __restrict__ rp8,
        const int2* __restrict__ csr,
        unsigned short* __restrict__ nout) {      // [N][KPAD] bf16
    const int node = (blockIdx.x * 256 + threadIdx.x) >> 5;
    const int lane = threadIdx.x & 31;
    const int ll = (lane < 25) ? lane : 24;       // load slot, clamped
    if (node >= N_NODES_C) return;
    const int beg = rp8[node];
    const int end = rp8[node + 1];                // beg + pad8(deg)
    const char* hb = (const char*)hin;
    float a0 = 0.0f, a1 = 0.0f, a2 = 0.0f, a3 = 0.0f;
    for (int k = beg; k < end; k += 8) {
        int2 e0 = csr[k];
        int2 e1 = csr[k + 1];
        int2 e2 = csr[k + 2];
        int2 e3 = csr[k + 3];
        int2 e4 = csr[k + 4];
        int2 e5 = csr[k + 5];
        int2 e6 = csr[k + 6];
        int2 e7 = csr[k + 7];
        uint2 x0 = ((const uint2*)(hb + (unsigned)e0.x))[ll];
        uint2 x1 = ((const uint2*)(hb + (unsigned)e1.x))[ll];
        uint2 x2 = ((const uint2*)(hb + (unsigned)e2.x))[ll];
        uint2 x3 = ((const uint2*)(hb + (unsigned)e3.x))[ll];
        uint2 x4 = ((const uint2*)(hb + (unsigned)e4.x))[ll];
        uint2 x5 = ((const uint2*)(hb + (unsigned)e5.x))[ll];
        uint2 x6 = ((const uint2*)(hb + (unsigned)e6.x))[ll];
        uint2 x7 = ((const uint2*)(hb + (unsigned)e7.x))[ll];
        float w0 = __int_as_float(e0.y);
        float w1 = __int_as_float(e1.y);
        float w2 = __int_as_float(e2.y);
        float w3 = __int_as_float(e3.y);
        float w4 = __int_as_float(e4.y);
        float w5 = __int_as_float(e5.y);
        float w6 = __int_as_float(e6.y);
        float w7 = __int_as_float(e7.y);
        a0 = fmaf(bflo(x0.x), w0, a0); a1 = fmaf(bfhi(x0.x), w0, a1);
        a2 = fmaf(bflo(x0.y), w0, a2); a3 = fmaf(bfhi(x0.y), w0, a3);
        a0 = fmaf(bflo(x1.x), w1, a0); a1 = fmaf(bfhi(x1.x), w1, a1);
        a2 = fmaf(bflo(x1.y), w1, a2); a3 = fmaf(bfhi(x1.y), w1, a3);
        a0 = fmaf(bflo(x2.x), w2, a0); a1 = fmaf(bfhi(x2.x), w2, a1);
        a2 = fmaf(bflo(x2.y), w2, a2); a3 = fmaf(bfhi(x2.y), w2, a3);
        a0 = fmaf(bflo(x3.x), w3, a0); a1 = fmaf(bfhi(x3.x), w3, a1);
        a2 = fmaf(bflo(x3.y), w3, a2); a3 = fmaf(bfhi(x3.y), w3, a3);
        a0 = fmaf(bflo(x4.x), w4, a0); a1 = fmaf(bfhi(x4.x), w4, a1);
        a2 = fmaf(bflo(x4.y), w4, a2); a3 = fmaf(bfhi(x4.y), w4, a3);
        a0 = fmaf(bflo(x5.x), w5, a0); a1 = fmaf(bfhi(x5.x), w5, a1);
        a2 = fmaf(bflo(x5.y), w5, a2); a3 = fmaf(bfhi(x5.y), w5, a3);
        a0 = fmaf(bflo(x6.x), w6, a0); a1 = fmaf(bfhi(x6.x), w6, a1);
        a2 = fmaf(bflo(x6.y), w6, a2); a3 = fmaf(bfhi(x6.y), w6, a3);
        a0 = fmaf(bflo(x7.x), w7, a0); a1 = fmaf(bfhi(x7.x), w7, a1);
        a2 = fmaf(bflo(x7.y), w7, a2); a3 = fmaf(bfhi(x7.y), w7, a3);
    }
    uint2 o = make_uint2(0u, 0u);
    if (lane < 25) {
        o.x = pack2(a0, a1);
        o.y = pack2(a2, a3);
    }
    ((uint2*)(nout + (size_t)node * KPAD))[lane] = o;
}

// ---------------------------------------------------------------------------
// MFMA dense: out[m][n] = act( sum_k A[m][k] * W[n][k] + b[n] )
// (round-14 proven, unchanged)
// ---------------------------------------------------------------------------
template <int NOUT, bool RELU, bool OUTBF>
__global__ __launch_bounds__(128) void dense_mfma_kernel(
        const unsigned short* __restrict__ A,     // [N][KPAD] bf16
        const unsigned short* __restrict__ Wp,    // [NT*16][KPAD] bf16
        const float* __restrict__ b,              // [NOUT]
        void* __restrict__ outp) {
    constexpr int NT = (NOUT == 100) ? 7 : 4;     // 16-col tiles

    const int tid = threadIdx.x;
    const int wid = tid >> 6;                     // 0,1
    const int lane = tid & 63;
    const int nl = lane & 15;
    const int kl8 = (lane >> 4) * 8;              // k offset of this lane's frag
    const int n0 = blockIdx.x * 32;
    const int arow = n0 + wid * 16 + nl;          // A row this lane loads

    // acc init = bias (C-in accumulates)
    f32x4 acc[NT];
    #pragma unroll
    for (int t = 0; t < NT; ++t) {
        int n = t * 16 + nl;
        float bt = (n < NOUT) ? b[n] : 0.0f;
        acc[t] = (f32x4){bt, bt, bt, bt};
    }

    const unsigned short* arow_p = A + (size_t)arow * KPAD + kl8;
    #pragma unroll
    for (int kk = 0; kk < 4; ++kk) {
        bf16x8 af = *(const bf16x8*)(arow_p + kk * 32);
        #pragma unroll
        for (int t = 0; t < NT; ++t) {
            bf16x8 bf = *(const bf16x8*)(Wp + (size_t)(t * 16 + nl) * KPAD + kk * 32 + kl8);
            acc[t] = __builtin_amdgcn_mfma_f32_16x16x32_bf16(af, bf, acc[t], 0, 0, 0);
        }
    }

    // Epilogue: D row = (l>>4)*4 + r within band
    const int rbase = n0 + wid * 16 + (lane >> 4) * 4;
    #pragma unroll
    for (int t = 0; t < NT; ++t) {
        const int n = t * 16 + nl;
        #pragma unroll
        for (int r = 0; r < 4; ++r) {
            float v = acc[t][r];
            if (RELU) v = fmaxf(v, 0.0f);
            const int row = rbase + r;
            if (OUTBF) {
                ((unsigned short*)outp)[(size_t)row * KPAD + n] =
                    (n < NOUT) ? f2bf(v) : (unsigned short)0;
            } else {
                if (n < NOUT) ((float*)outp)[(size_t)row * NOUT + n] = v;
            }
        }
    }
    if (OUTBF) {
        // zero pad cols [112,128) for this wave's 16 rows (4 lanes x 8B per row)
        const int zrow = n0 + wid * 16 + (lane >> 2);
        uint2* zp = (uint2*)((unsigned short*)outp + (size_t)zrow * KPAD + 112 + (lane & 3) * 4);
        *zp = make_uint2(0u, 0u);
    }
}

// ---------------------------------------------------------------------------
extern "C" void kernel_launch(void* const* d_in, const int* in_sizes, int n_in,
                              void* d_out, int out_size, void* d_ws, size_t ws_size,
                              hipStream_t stream) {
    const float* features = (const float*)d_in[0];
    const int*   node_ids = (const int*)d_in[1];
    const int*   src      = (const int*)d_in[2];
    const int*   dst      = (const int*)d_in[3];
    const float* ew       = (const float*)d_in[4];
    const float* alpha    = (const float*)d_in[5];
    const float* W1       = (const float*)d_in[6];
    const float* b1       = (const float*)d_in[7];
    const float* W2       = (const float*)d_in[8];
    const float* b2       = (const float*)d_in[9];
    const float* lin_w    = (const float*)d_in[10];
    const float* lin_b    = (const float*)d_in[11];
    float* out = (float*)d_out;

    char* ws = (char*)d_ws;
    size_t off = 0;
    auto alloc = [&](size_t bytes) {
        void* p = ws + off;
        off += (bytes + 255) & ~(size_t)255;
        return p;
    };
    int*   cnt     = (int*)alloc((size_t)N_NODES_C * 4);        // atomic counters == deg
    int*   sdeg    = (int*)alloc((size_t)N_NODES_C * 4);
    int*   bsum    = (int*)alloc((size_t)SCAN_NBLK * 4);
    int*   rp8     = (int*)alloc((size_t)(N_NODES_C + 1) * 4);
    int2*  rpc     = (int2*)alloc((size_t)N_NODES_C * 8);       // (start, invd)
    int2*  staging = (int2*)alloc((size_t)N_EDGES_C * 8);       // (pos, scale)
    int2*  csr     = (int2*)alloc((size_t)CSR_CAP * 8);
    unsigned short* fbf     = (unsigned short*)alloc((size_t)N_NODES_C * KPAD * 2);
    unsigned short* h1      = (unsigned short*)alloc((size_t)N_NODES_C * KPAD * 2);
    unsigned short* neigh_b = (unsigned short*)alloc((size_t)N_NODES_C * KPAD * 2);
    unsigned short* Wp1     = (unsigned short*)alloc((size_t)112 * KPAD * 2);
    unsigned short* Wp2     = (unsigned short*)alloc((size_t)112 * KPAD * 2);
    unsigned short* LWp     = (unsigned short*)alloc((size_t)64 * KPAD * 2);
    // h2 aliases fbf: fbf is dead after aggregate-1 reads it.
    unsigned short* h2 = fbf;
    (void)ws_size;

    // --- prep: memsets -> single-atomic-pass mega_prep ---
    hipMemsetAsync(cnt, 0, (size_t)N_NODES_C * 4, stream);
    hipMemsetAsync(csr, 0, (size_t)CSR_CAP * 8, stream);
    mega_prep_kernel<<<MEGA_BLKS, 256, 0, stream>>>(
        features, node_ids, src, dst, ew, alpha,
        fbf, cnt, staging, W1, W2, lin_w, Wp1, Wp2, LWp);
    scan1_kernel<<<SCAN_NBLK, SCAN_BLK, 0, stream>>>(cnt, sdeg, bsum);
    scan3_kernel<<<SCAN_NBLK, SCAN_BLK, 0, stream>>>(sdeg, bsum, cnt, rp8, rpc);
    placement_kernel<<<EDGE_BLKS, 256, 0, stream>>>(src, dst, staging, rpc, csr);

    // --- Layer 1 ---
    aggregate_kernel<<<(N_NODES_C * 32) / 256, 256, 0, stream>>>(fbf, rp8, csr, neigh_b);
    dense_mfma_kernel<FEATS, true, true><<<N_NODES_C / 32, 128, 0, stream>>>(
        neigh_b, Wp1, b1, h1);

    // --- Layer 2 ---
    aggregate_kernel<<<(N_NODES_C * 32) / 256, 256, 0, stream>>>(h1, rp8, csr, neigh_b);
    dense_mfma_kernel<FEATS, true, true><<<N_NODES_C / 32, 128, 0, stream>>>(
        neigh_b, Wp2, b2, h2);

    // --- Classifier ---
    dense_mfma_kernel<NCLS, false, false><<<N_NODES_C / 32, 128, 0, stream>>>(
        h2, LWp, lin_b, out);
}

// Round 22
// 236.294 us; speedup vs baseline: 1.2496x; 1.0121x over previous
//
#include <hip/hip_runtime.h>

#define N_NODES_C 100000
#define N_EDGES_C 800000
#define FEATS 100
#define NCLS 50
#define GENE 20000
#define SCAN_BLK 1024
#define SCAN_NBLK ((N_NODES_C + SCAN_BLK - 1) / SCAN_BLK)   // 98
#define KPAD 128                                             // padded K (4 x 32)
#define CSR_CAP 1600000                                      // 800K + 8*100K pad bound
// edge-parallel kernels: 4 edges/thread, 256 threads
#define EDGE_BLKS ((N_EDGES_C + 1023) / 1024)                // 782
// mega_prep block ranges: edge section FIRST (atomic pole), streams fill around
#define CSRZ_ENTRIES_PER_BLK 2048                            // 256 thr x 4 int4
#define CSRZ_BLKS ((CSR_CAP + CSRZ_ENTRIES_PER_BLK - 1) / CSRZ_ENTRIES_PER_BLK) // 782
#define CONV_SLOTS (N_NODES_C * 32)                          // 3.2M uint2 slots
#define CONV_BLKS ((CONV_SLOTS + 2047) / 2048)               // 1563 (8 slots/thread)
#define WPREP_BLKS 8
#define MEGA_BLKS (EDGE_BLKS + CSRZ_BLKS + CONV_BLKS + WPREP_BLKS)

typedef short bf16x8 __attribute__((ext_vector_type(8)));
typedef float f32x4  __attribute__((ext_vector_type(4)));

// bf16 helpers (RNE pack, shift-unpack)
__device__ __forceinline__ unsigned short f2bf(float f) {
    unsigned int x = __float_as_uint(f);
    return (unsigned short)((x + 0x7FFFu + ((x >> 16) & 1u)) >> 16);
}
__device__ __forceinline__ unsigned int pack2(float lo, float hi) {
    return (unsigned int)f2bf(lo) | ((unsigned int)f2bf(hi) << 16);
}
__device__ __forceinline__ float bflo(unsigned int u) { return __uint_as_float(u << 16); }
__device__ __forceinline__ float bfhi(unsigned int u) { return __uint_as_float(u & 0xFFFF0000u); }

// ---------------------------------------------------------------------------
// mega_prep v4: single atomic pass + all prep streams, block-range dispatched.
//   [0, EDGE)             : per edge: scale_noinv = alpha[idx]*ew,
//                           pos = atomicAdd(&cnt[dst],1), staging[e]=(pos,sc).
//                           cnt doubles as deg. The ONLY atomic pass.
//   [EDGE, +CSRZ)         : zero csr (12.8 MB) — replaces the hipMemsetAsync;
//                           stream writes hide under the atomic pole.
//   [+CSRZ, +CONV)        : features f32 [N][100] -> bf16 [N][KPAD], 8 slots/thr
//   [+CONV, +WPREP)       : pad W1/W2 -> [112][KPAD], lin_w -> [64][KPAD]
// cnt is memset to 0 by the preceding stream op.
// ---------------------------------------------------------------------------
__global__ __launch_bounds__(256) void mega_prep_kernel(
        const float* __restrict__ features,
        const int* __restrict__ node_ids,
        const int* __restrict__ src,
        const int* __restrict__ dst,
        const float* __restrict__ ew,
        const float* __restrict__ alpha,
        unsigned short* __restrict__ fbf,
        int* __restrict__ cnt,
        int2* __restrict__ staging,
        int2* __restrict__ csr,
        const float* __restrict__ W1,
        const float* __restrict__ W2,
        const float* __restrict__ LW,
        unsigned short* __restrict__ Wp1,
        unsigned short* __restrict__ Wp2,
        unsigned short* __restrict__ LWp) {
    const int bid = blockIdx.x;
    const int tid = threadIdx.x;

    if (bid < EDGE_BLKS) {
        // ---- single atomic pass: count + scale + staging ----
        const int e = bid * 1024 + tid * 4;
        if (e < N_EDGES_C) {                      // N_EDGES_C % 4 == 0
            int4   s4 = *reinterpret_cast<const int4*>(src + e);
            int4   d4 = *reinterpret_cast<const int4*>(dst + e);
            float4 w4 = *reinterpret_cast<const float4*>(ew + e);
            const int   ss[4] = {s4.x, s4.y, s4.z, s4.w};
            const int   ds[4] = {d4.x, d4.y, d4.z, d4.w};
            const float we[4] = {w4.x, w4.y, w4.z, w4.w};
            int sid[4], did[4];
            #pragma unroll
            for (int i = 0; i < 4; ++i) sid[i] = node_ids[ss[i]];
            #pragma unroll
            for (int i = 0; i < 4; ++i) did[i] = node_ids[ds[i]];
            int pos[4];
            float sc[4];
            #pragma unroll
            for (int i = 0; i < 4; ++i) {
                int idx = GENE + 1;                              // cell-cell
                if (sid[i] >= 0 && did[i] < 0) idx = sid[i];     // gene -> cell
                else if (did[i] >= 0 && sid[i] < 0) idx = did[i];// cell -> gene
                else if (did[i] >= 0 && sid[i] >= 0) idx = GENE; // gene -> gene
                sc[i] = alpha[idx] * we[i];
                pos[i] = atomicAdd(&cnt[ds[i]], 1);
            }
            int4 st01 = make_int4(pos[0], __float_as_int(sc[0]),
                                  pos[1], __float_as_int(sc[1]));
            int4 st23 = make_int4(pos[2], __float_as_int(sc[2]),
                                  pos[3], __float_as_int(sc[3]));
            reinterpret_cast<int4*>(staging)[(e >> 1)]     = st01;
            reinterpret_cast<int4*>(staging)[(e >> 1) + 1] = st23;
        }
    } else if (bid < EDGE_BLKS + CSRZ_BLKS) {
        // ---- zero csr (pad entries decode as row 0 / weight 0) ----
        const int b2 = bid - EDGE_BLKS;
        int4* p = reinterpret_cast<int4*>(csr);   // 2 entries per int4
        const int base = b2 * 1024 + tid;         // int4 index, stride 256
        const int nInt4 = CSR_CAP / 2;            // 800000
        #pragma unroll
        for (int j = 0; j < 4; ++j) {
            int i = base + j * 256;
            if (i < nInt4) p[i] = make_int4(0, 0, 0, 0);
        }
    } else if (bid < EDGE_BLKS + CSRZ_BLKS + CONV_BLKS) {
        // ---- feature conversion, 8 slots/thread ----
        const int base = (bid - EDGE_BLKS - CSRZ_BLKS) * 2048;
        #pragma unroll
        for (int j = 0; j < 8; ++j) {
            int i = base + j * 256 + tid;
            if (i >= CONV_SLOTS) break;
            int node = i >> 5;
            int sl = i & 31;
            uint2 o = make_uint2(0u, 0u);
            if (sl < 25) {
                float4 v = reinterpret_cast<const float4*>(features + (size_t)node * FEATS)[sl];
                o.x = pack2(v.x, v.y);
                o.y = pack2(v.z, v.w);
            }
            reinterpret_cast<uint2*>(fbf + (size_t)node * KPAD)[sl] = o;
        }
    } else {
        // ---- weight pad/convert ----
        const int wb = bid - (EDGE_BLKS + CSRZ_BLKS + CONV_BLKS);
        for (int i = wb * 256 + tid; i < 112 * KPAD; i += WPREP_BLKS * 256) {
            int r = i >> 7;
            int c = i & 127;
            bool in100 = (r < 100) && (c < 100);
            Wp1[i] = in100 ? f2bf(W1[r * 100 + c]) : (unsigned short)0;
            Wp2[i] = in100 ? f2bf(W2[r * 100 + c]) : (unsigned short)0;
            if (r < 64) {
                LWp[i] = (r < NCLS && c < 100) ? f2bf(LW[r * 100 + c]) : (unsigned short)0;
            }
        }
    }
}

// ---------------------------------------------------------------------------
// scan1: inclusive scan of pad8(cnt) per 1024-block -> sdeg, block totals.
// cnt itself is preserved (scan3 derives inv_deg from it).
// ---------------------------------------------------------------------------
__global__ __launch_bounds__(1024) void scan1_kernel(const int* __restrict__ cnt,
                                                     int* __restrict__ sdeg,
                                                     int* __restrict__ bsum) {
    __shared__ int wsum[16];
    const int i = blockIdx.x * SCAN_BLK + threadIdx.x;
    const int lane = threadIdx.x & 63;
    const int wid = threadIdx.x >> 6;
    int v = (i < N_NODES_C) ? ((cnt[i] + 7) & ~7) : 0;   // padded degree
    #pragma unroll
    for (int d = 1; d < 64; d <<= 1) {
        int t = __shfl_up(v, d);
        if (lane >= d) v += t;
    }
    if (lane == 63) wsum[wid] = v;
    __syncthreads();
    if (wid == 0) {
        int s = (lane < 16) ? wsum[lane] : 0;
        #pragma unroll
        for (int d = 1; d < 16; d <<= 1) {
            int t = __shfl_up(s, d);
            if (lane >= d) s += t;
        }
        if (lane < 16) wsum[lane] = s;
    }
    __syncthreads();
    if (wid > 0) v += wsum[wid - 1];
    if (i < N_NODES_C) sdeg[i] = v;
    if (threadIdx.x == SCAN_BLK - 1) bsum[blockIdx.x] = v;
}

// ---------------------------------------------------------------------------
// scan3 (scan2 folded in): rp8 = exclusive padded offsets (for aggregate);
// rpc[node] = (bucket_start, inv_deg as float bits) for placement (1 gather).
// ---------------------------------------------------------------------------
__global__ __launch_bounds__(1024) void scan3_kernel(const int* __restrict__ sdeg,
                                                     const int* __restrict__ bsum,
                                                     const int* __restrict__ cnt,
                                                     int* __restrict__ rp8,
                                                     int2* __restrict__ rpc) {
    __shared__ int boff[SCAN_NBLK];
    if (threadIdx.x < SCAN_NBLK) boff[threadIdx.x] = bsum[threadIdx.x];
    __syncthreads();
    if (threadIdx.x == 0) {
        int off = 0;
        #pragma unroll 1
        for (int j = 0; j < SCAN_NBLK; ++j) { int t = boff[j]; boff[j] = off; off += t; }
    }
    __syncthreads();
    int i = blockIdx.x * SCAN_BLK + threadIdx.x;
    if (i >= N_NODES_C) return;
    int v = sdeg[i] + boff[blockIdx.x];           // inclusive padded sum
    rp8[i + 1] = v;
    int dg = cnt[i];
    int pd = (dg + 7) & ~7;
    float invd = (dg > 0) ? 1.0f / (float)dg : 0.0f;
    rpc[i] = make_int2(v - pd, __float_as_int(invd));
    if (i == 0) rp8[0] = 0;
}

// ---------------------------------------------------------------------------
// Placement: NO atomics. Streaming reads (src, dst, staging), one rpc
// gather per edge, scatter csr[start + pos] = (src*256, scale*inv_deg).
// Buckets padded to x8; csr pre-zeroed so pads decode as (row 0, weight 0).
// ---------------------------------------------------------------------------
__global__ __launch_bounds__(256) void placement_kernel(
        const int* __restrict__ src,
        const int* __restrict__ dst,
        const int2* __restrict__ staging,
        const int2* __restrict__ rpc,
        int2* __restrict__ csr) {
    const int e = blockIdx.x * 1024 + threadIdx.x * 4;
    if (e >= N_EDGES_C) return;                   // N_EDGES_C % 4 == 0
    int4 s4 = *reinterpret_cast<const int4*>(src + e);
    int4 d4 = *reinterpret_cast<const int4*>(dst + e);
    int4 st01 = reinterpret_cast<const int4*>(staging)[(e >> 1)];
    int4 st23 = reinterpret_cast<const int4*>(staging)[(e >> 1) + 1];
    const int   ss[4]  = {s4.x, s4.y, s4.z, s4.w};
    const int   ds[4]  = {d4.x, d4.y, d4.z, d4.w};
    const int   pos[4] = {st01.x, st01.z, st23.x, st23.z};
    const float sc[4]  = {__int_as_float(st01.y), __int_as_float(st01.w),
                          __int_as_float(st23.y), __int_as_float(st23.w)};
    #pragma unroll
    for (int i = 0; i < 4; ++i) {
        int2 rc = rpc[ds[i]];
        float v = sc[i] * __int_as_float(rc.y);
        csr[rc.x + pos[i]] = make_int2(ss[i] << 8, __float_as_int(v));
    }
}

// ---------------------------------------------------------------------------
// Aggregation bf16->bf16 (stride KPAD): 2 nodes/wave, 32 lanes each own a
// uint2 (4 bf16 cols), 8-deep unroll, NO clamps/selects (zero-padded x8
// buckets), inv_deg folded into scale. csr.x is a precomputed byte offset.
// (r20-proven, unchanged)
// ---------------------------------------------------------------------------
__global__ __launch_bounds__(256) void aggregate_kernel(
        const unsigned short* __restrict__ hin,   // [N][KPAD] bf16
        const int* __restrict__ rp8,
        const int2* __restrict__ csr,
        unsigned short* __restrict__ nout) {      // [N][KPAD] bf16
    const int node = (blockIdx.x * 256 + threadIdx.x) >> 5;
    const int lane = threadIdx.x & 31;
    const int ll = (lane < 25) ? lane : 24;       // load slot, clamped
    if (node >= N_NODES_C) return;
    const int beg = rp8[node];
    const int end = rp8[node + 1];                // beg + pad8(deg)
    const char* hb = (const char*)hin;
    float a0 = 0.0f, a1 = 0.0f, a2 = 0.0f, a3 = 0.0f;
    for (int k = beg; k < end; k += 8) {
        int2 e0 = csr[k];
        int2 e1 = csr[k + 1];
        int2 e2 = csr[k + 2];
        int2 e3 = csr[k + 3];
        int2 e4 = csr[k + 4];
        int2 e5 = csr[k + 5];
        int2 e6 = csr[k + 6];
        int2 e7 = csr[k + 7];
        uint2 x0 = ((const uint2*)(hb + (unsigned)e0.x))[ll];
        uint2 x1 = ((const uint2*)(hb + (unsigned)e1.x))[ll];
        uint2 x2 = ((const uint2*)(hb + (unsigned)e2.x))[ll];
        uint2 x3 = ((const uint2*)(hb + (unsigned)e3.x))[ll];
        uint2 x4 = ((const uint2*)(hb + (unsigned)e4.x))[ll];
        uint2 x5 = ((const uint2*)(hb + (unsigned)e5.x))[ll];
        uint2 x6 = ((const uint2*)(hb + (unsigned)e6.x))[ll];
        uint2 x7 = ((const uint2*)(hb + (unsigned)e7.x))[ll];
        float w0 = __int_as_float(e0.y);
        float w1 = __int_as_float(e1.y);
        float w2 = __int_as_float(e2.y);
        float w3 = __int_as_float(e3.y);
        float w4 = __int_as_float(e4.y);
        float w5 = __int_as_float(e5.y);
        float w6 = __int_as_float(e6.y);
        float w7 = __int_as_float(e7.y);
        a0 = fmaf(bflo(x0.x), w0, a0); a1 = fmaf(bfhi(x0.x), w0, a1);
        a2 = fmaf(bflo(x0.y), w0, a2); a3 = fmaf(bfhi(x0.y), w0, a3);
        a0 = fmaf(bflo(x1.x), w1, a0); a1 = fmaf(bfhi(x1.x), w1, a1);
        a2 = fmaf(bflo(x1.y), w1, a2); a3 = fmaf(bfhi(x1.y), w1, a3);
        a0 = fmaf(bflo(x2.x), w2, a0); a1 = fmaf(bfhi(x2.x), w2, a1);
        a2 = fmaf(bflo(x2.y), w2, a2); a3 = fmaf(bfhi(x2.y), w2, a3);
        a0 = fmaf(bflo(x3.x), w3, a0); a1 = fmaf(bfhi(x3.x), w3, a1);
        a2 = fmaf(bflo(x3.y), w3, a2); a3 = fmaf(bfhi(x3.y), w3, a3);
        a0 = fmaf(bflo(x4.x), w4, a0); a1 = fmaf(bfhi(x4.x), w4, a1);
        a2 = fmaf(bflo(x4.y), w4, a2); a3 = fmaf(bfhi(x4.y), w4, a3);
        a0 = fmaf(bflo(x5.x), w5, a0); a1 = fmaf(bfhi(x5.x), w5, a1);
        a2 = fmaf(bflo(x5.y), w5, a2); a3 = fmaf(bfhi(x5.y), w5, a3);
        a0 = fmaf(bflo(x6.x), w6, a0); a1 = fmaf(bfhi(x6.x), w6, a1);
        a2 = fmaf(bflo(x6.y), w6, a2); a3 = fmaf(bfhi(x6.y), w6, a3);
        a0 = fmaf(bflo(x7.x), w7, a0); a1 = fmaf(bfhi(x7.x), w7, a1);
        a2 = fmaf(bflo(x7.y), w7, a2); a3 = fmaf(bfhi(x7.y), w7, a3);
    }
    uint2 o = make_uint2(0u, 0u);
    if (lane < 25) {
        o.x = pack2(a0, a1);
        o.y = pack2(a2, a3);
    }
    ((uint2*)(nout + (size_t)node * KPAD))[lane] = o;
}

// ---------------------------------------------------------------------------
// MFMA dense: out[m][n] = act( sum_k A[m][k] * W[n][k] + b[n] )
// (round-14 proven, unchanged)
// ---------------------------------------------------------------------------
template <int NOUT, bool RELU, bool OUTBF>
__global__ __launch_bounds__(128) void dense_mfma_kernel(
        const unsigned short* __restrict__ A,     // [N][KPAD] bf16
        const unsigned short* __restrict__ Wp,    // [NT*16][KPAD] bf16
        const float* __restrict__ b,              // [NOUT]
        void* __restrict__ outp) {
    constexpr int NT = (NOUT == 100) ? 7 : 4;     // 16-col tiles

    const int tid = threadIdx.x;
    const int wid = tid >> 6;                     // 0,1
    const int lane = tid & 63;
    const int nl = lane & 15;
    const int kl8 = (lane >> 4) * 8;              // k offset of this lane's frag
    const int n0 = blockIdx.x * 32;
    const int arow = n0 + wid * 16 + nl;          // A row this lane loads

    // acc init = bias (C-in accumulates)
    f32x4 acc[NT];
    #pragma unroll
    for (int t = 0; t < NT; ++t) {
        int n = t * 16 + nl;
        float bt = (n < NOUT) ? b[n] : 0.0f;
        acc[t] = (f32x4){bt, bt, bt, bt};
    }

    const unsigned short* arow_p = A + (size_t)arow * KPAD + kl8;
    #pragma unroll
    for (int kk = 0; kk < 4; ++kk) {
        bf16x8 af = *(const bf16x8*)(arow_p + kk * 32);
        #pragma unroll
        for (int t = 0; t < NT; ++t) {
            bf16x8 bf = *(const bf16x8*)(Wp + (size_t)(t * 16 + nl) * KPAD + kk * 32 + kl8);
            acc[t] = __builtin_amdgcn_mfma_f32_16x16x32_bf16(af, bf, acc[t], 0, 0, 0);
        }
    }

    // Epilogue: D row = (l>>4)*4 + r within band
    const int rbase = n0 + wid * 16 + (lane >> 4) * 4;
    #pragma unroll
    for (int t = 0; t < NT; ++t) {
        const int n = t * 16 + nl;
        #pragma unroll
        for (int r = 0; r < 4; ++r) {
            float v = acc[t][r];
            if (RELU) v = fmaxf(v, 0.0f);
            const int row = rbase + r;
            if (OUTBF) {
                ((unsigned short*)outp)[(size_t)row * KPAD + n] =
                    (n < NOUT) ? f2bf(v) : (unsigned short)0;
            } else {
                if (n < NOUT) ((float*)outp)[(size_t)row * NOUT + n] = v;
            }
        }
    }
    if (OUTBF) {
        // zero pad cols [112,128) for this wave's 16 rows (4 lanes x 8B per row)
        const int zrow = n0 + wid * 16 + (lane >> 2);
        uint2* zp = (uint2*)((unsigned short*)outp + (size_t)zrow * KPAD + 112 + (lane & 3) * 4);
        *zp = make_uint2(0u, 0u);
    }
}

// ---------------------------------------------------------------------------
extern "C" void kernel_launch(void* const* d_in, const int* in_sizes, int n_in,
                              void* d_out, int out_size, void* d_ws, size_t ws_size,
                              hipStream_t stream) {
    const float* features = (const float*)d_in[0];
    const int*   node_ids = (const int*)d_in[1];
    const int*   src      = (const int*)d_in[2];
    const int*   dst      = (const int*)d_in[3];
    const float* ew       = (const float*)d_in[4];
    const float* alpha    = (const float*)d_in[5];
    const float* W1       = (const float*)d_in[6];
    const float* b1       = (const float*)d_in[7];
    const float* W2       = (const float*)d_in[8];
    const float* b2       = (const float*)d_in[9];
    const float* lin_w    = (const float*)d_in[10];
    const float* lin_b    = (const float*)d_in[11];
    float* out = (float*)d_out;

    char* ws = (char*)d_ws;
    size_t off = 0;
    auto alloc = [&](size_t bytes) {
        void* p = ws + off;
        off += (bytes + 255) & ~(size_t)255;
        return p;
    };
    int*   cnt     = (int*)alloc((size_t)N_NODES_C * 4);        // atomic counters == deg
    int*   sdeg    = (int*)alloc((size_t)N_NODES_C * 4);
    int*   bsum    = (int*)alloc((size_t)SCAN_NBLK * 4);
    int*   rp8     = (int*)alloc((size_t)(N_NODES_C + 1) * 4);
    int2*  rpc     = (int2*)alloc((size_t)N_NODES_C * 8);       // (start, invd)
    int2*  staging = (int2*)alloc((size_t)N_EDGES_C * 8);       // (pos, scale)
    int2*  csr     = (int2*)alloc((size_t)CSR_CAP * 8);
    unsigned short* fbf     = (unsigned short*)alloc((size_t)N_NODES_C * KPAD * 2);
    unsigned short* h1      = (unsigned short*)alloc((size_t)N_NODES_C * KPAD * 2);
    unsigned short* neigh_b = (unsigned short*)alloc((size_t)N_NODES_C * KPAD * 2);
    unsigned short* Wp1     = (unsigned short*)alloc((size_t)112 * KPAD * 2);
    unsigned short* Wp2     = (unsigned short*)alloc((size_t)112 * KPAD * 2);
    unsigned short* LWp     = (unsigned short*)alloc((size_t)64 * KPAD * 2);
    // h2 aliases fbf: fbf is dead after aggregate-1 reads it.
    unsigned short* h2 = fbf;
    (void)ws_size;

    // --- prep: cnt memset -> mega_prep (atomics + csr-zero + conversions) ---
    hipMemsetAsync(cnt, 0, (size_t)N_NODES_C * 4, stream);
    mega_prep_kernel<<<MEGA_BLKS, 256, 0, stream>>>(
        features, node_ids, src, dst, ew, alpha,
        fbf, cnt, staging, csr, W1, W2, lin_w, Wp1, Wp2, LWp);
    scan1_kernel<<<SCAN_NBLK, SCAN_BLK, 0, stream>>>(cnt, sdeg, bsum);
    scan3_kernel<<<SCAN_NBLK, SCAN_BLK, 0, stream>>>(sdeg, bsum, cnt, rp8, rpc);
    placement_kernel<<<EDGE_BLKS, 256, 0, stream>>>(src, dst, staging, rpc, csr);

    // --- Layer 1 ---
    aggregate_kernel<<<(N_NODES_C * 32) / 256, 256, 0, stream>>>(fbf, rp8, csr, neigh_b);
    dense_mfma_kernel<FEATS, true, true><<<N_NODES_C / 32, 128, 0, stream>>>(
        neigh_b, Wp1, b1, h1);

    // --- Layer 2 ---
    aggregate_kernel<<<(N_NODES_C * 32) / 256, 256, 0, stream>>>(h1, rp8, csr, neigh_b);
    dense_mfma_kernel<FEATS, true, true><<<N_NODES_C / 32, 128, 0, stream>>>(
        neigh_b, Wp2, b2, h2);

    // --- Classifier ---
    dense_mfma_kernel<NCLS, false, false><<<N_NODES_C / 32, 128, 0, stream>>>(
        h2, LWp, lin_b, out);
}